// Round 9
// baseline (23416.325 us; speedup 1.0000x reference)
//
#include <hip/hip_runtime.h>
#include <hip/hip_bf16.h>
#include <cstdint>
#include <cstddef>

// ---------------------------------------------------------------------------
// ConditionalSmilesRnn: 3-layer LSTM, H=1024, B=256, T=128, greedy decode.
// Round 9: MEGA-KERNEL — all 128 steps x (3 layers + decode) in ONE launch.
//   - grid 256 x 512 thr, 64KB LDS, <=128 VGPR -> all blocks co-resident
//   - two-level grid barrier (8 padded group counters -> global generation),
//     agent-scope acq/rel atomics (mechanism validated in R7), per-wave
//     acquire (buffer_inv) after each barrier before remote reads
//   - layer body = R8's validated fp16x3 pre-split pipeline, verbatim
//   - ping-pong h buffers retained; legacy R4 fallback if ws too small
// ---------------------------------------------------------------------------

#define BB 256
#define TT 128
#define OO 47

typedef __attribute__((ext_vector_type(8))) _Float16 f16x8;
typedef __attribute__((ext_vector_type(4))) float f32x4;

// ---- workspace byte offsets ----
#define CBUF_B   0u                    // [3][256][1024] f32
#define HF32_B   3145728u              // [3][2][256][1024] f32
#define BCOMB_B  9437184u              // [3][4096] f32
#define EHI_B    9486336u              // [16][33][512] f16 slabs
#define ELO_B    10027008u
#define HS_B     10567680u             // [3][2][2] x 524288 B
#define W_B      16859136u
#define BAR_B    118046720u            // 160 u32 barrier state
#define WS_NEEDED 118047360u

#define BARRIER() asm volatile("s_barrier" ::: "memory")
#define WAITV(n)  asm volatile("s_waitcnt vmcnt(" #n ")" ::: "memory")
#define WAITLGKM0() asm volatile("s_waitcnt lgkmcnt(0)" ::: "memory")

__device__ __forceinline__ float fsig(float x) {
  return 1.0f / (1.0f + exp2f(-1.4426950408889634f * x));
}
__device__ __forceinline__ float ftanhf(float x) {
  float e = exp2f(2.8853900817779268f * x);
  return 1.0f - 2.0f / (e + 1.0f);
}
__device__ __forceinline__ unsigned short f16b(_Float16 h) {
  union { _Float16 f; unsigned short u; } c; c.f = h; return c.u;
}
__device__ __forceinline__ void gld16(const void* g, void* l) {
  __builtin_amdgcn_global_load_lds(
      (const __attribute__((address_space(1))) unsigned int*)g,
      (__attribute__((address_space(3))) unsigned int*)l, 16, 0, 0);
}
// slab address (f16 units) for element (k, r) of group grp
__device__ __forceinline__ size_t slab_addr(int grp, int NCH, int k, int r) {
  return ((size_t)grp * NCH + (k >> 5)) * 512 + ((k >> 4) & 1) * 256 +
         ((k >> 3) & 1) * 128 + r * 8 + (k & 7);
}

// ---------------------------------------------------------------------------
__global__ void k_zero(float* p, int n) {
  int i = blockIdx.x * blockDim.x + threadIdx.x;
  int stride = gridDim.x * blockDim.x;
  for (; i < n; i += stride) p[i] = 0.0f;
}

__global__ void k_binit(float* bc, const float* __restrict__ bih,
                        const float* __restrict__ bhh, unsigned* bar) {
  int i = blockIdx.x * blockDim.x + threadIdx.x;
  if (i < 12288) bc[i] = bih[i] + bhh[i];
  if (i < 160) bar[i] = 0u;
}

// split fp32 weight matrix [4096][K] into slab-ordered f16 hi/lo (zero pad)
__global__ void k_prepw(const float* __restrict__ src, unsigned short* dhi,
                        unsigned short* dlo, int K, int NCH) {
  const int nrow = blockIdx.x;
  const int ngrp = nrow >> 4, rr = nrow & 15;
  const float* s = src + (size_t)nrow * K;
  for (int k = threadIdx.x; k < NCH * 32; k += blockDim.x) {
    float val = (k < K) ? s[k] : 0.0f;
    _Float16 h16 = (_Float16)val;
    _Float16 l16 = (_Float16)((val - (float)h16) * 2048.0f);
    size_t a = slab_addr(ngrp, NCH, k, rr);
    dhi[a] = f16b(h16);
    dlo[a] = f16b(l16);
  }
}

// E = [emb(tok 0) | props | pad] split into slabs (NCH=33)
__global__ void k_einit(unsigned short* ehi, unsigned short* elo,
                        const float* __restrict__ emb,
                        const float* __restrict__ props) {
  const int b = blockIdx.x;
  for (int j = threadIdx.x; j < 1056; j += blockDim.x) {
    float val = (j < 1024) ? emb[j] : (j < 1028 ? props[b * 4 + (j - 1024)] : 0.0f);
    _Float16 h16 = (_Float16)val;
    _Float16 l16 = (_Float16)((val - (float)h16) * 2048.0f);
    size_t a = slab_addr(b >> 4, 33, j, b & 15);
    ehi[a] = f16b(h16);
    elo[a] = f16b(l16);
  }
}

// ---------------------------------------------------------------------------
// two-level grid barrier (256 blocks): 8 padded group counters -> global gen.
__device__ __forceinline__ void gbar(unsigned* bar, int bid) {
  __syncthreads();
  if (threadIdx.x == 0) {
    unsigned* gen  = bar + 144;
    unsigned* gcnt = bar + 128;
    unsigned* myg  = bar + ((bid & 7) << 4);
    unsigned g = __hip_atomic_load(gen, __ATOMIC_RELAXED, __HIP_MEMORY_SCOPE_AGENT);
    unsigned o = __hip_atomic_fetch_add(myg, 1u, __ATOMIC_ACQ_REL, __HIP_MEMORY_SCOPE_AGENT);
    if (o == 31u) {
      __hip_atomic_store(myg, 0u, __ATOMIC_RELAXED, __HIP_MEMORY_SCOPE_AGENT);
      unsigned og = __hip_atomic_fetch_add(gcnt, 1u, __ATOMIC_ACQ_REL, __HIP_MEMORY_SCOPE_AGENT);
      if (og == 7u) {
        __hip_atomic_store(gcnt, 0u, __ATOMIC_RELAXED, __HIP_MEMORY_SCOPE_AGENT);
        __hip_atomic_store(gen, g + 1u, __ATOMIC_RELEASE, __HIP_MEMORY_SCOPE_AGENT);
      }
    }
    while (__hip_atomic_load(gen, __ATOMIC_RELAXED, __HIP_MEMORY_SCOPE_AGENT) == g) {
      asm volatile("s_sleep 2");
    }
    (void)__hip_atomic_load(gen, __ATOMIC_ACQUIRE, __HIP_MEMORY_SCOPE_AGENT);
  }
  __syncthreads();
  // per-wave acquire: invalidate caches before reading remote data
  if ((threadIdx.x & 63) == 0)
    (void)__hip_atomic_load(bar + 144, __ATOMIC_ACQUIRE, __HIP_MEMORY_SCOPE_AGENT);
}

// ---------------------------------------------------------------------------
// MEGA kernel: 128 steps x (3 fused layer phases + decode phase).
__global__ __launch_bounds__(512, 4) void k_mega(
    char* __restrict__ base, const float* __restrict__ Wdec,
    const float* __restrict__ bdec, const float* __restrict__ emb,
    float* __restrict__ out) {
  __shared__ char LBUF[65536];
  const int tid = threadIdx.x;
  const int lane = tid & 63, wid = tid >> 6;
  const int bid = blockIdx.x;
  const int sw = ((bid & 7) << 5) + (bid >> 3);    // XCD swizzle
  const int mt = sw & 3, nt = sw >> 2;
  const int m0 = mt << 6, h0c = nt << 4;

  unsigned* bar = (unsigned*)(base + BAR_B);
  float* cbufA = (float*)(base + CBUF_B);
  float* hfA   = (float*)(base + HF32_B);
  float* bcA   = (float*)(base + BCOMB_B);

  // weight slab offsets (bytes)
  const unsigned wOff[12] = {
    16859136u, 25509888u, 34160640u, 42549248u, 50937856u, 59326464u,
    67715072u, 76103680u, 84492288u, 92880896u, 101269504u, 109658112u};

  // roles (constant across phases)
  const int sIsB = wid >> 2, sHalfW = (wid >> 1) & 1, sPrec = wid & 1;
  const int ldsoff0 = (sIsB << 14) + (sHalfW << 13) + (sPrec << 12);
  const int wHalf = wid >> 2, q = wid & 3;
  const int mb = (q >> 1) << 1, nbb = (q & 1) << 1;
  const int mrow0 = ((q >> 1) << 5) + ((lane >> 4) << 2);
  const int ncol0 = ((q & 1) << 5) + (lane & 15);
  const float LSC = 1.0f / 2048.0f;

  for (int t = 0; t < TT; ++t) {
    const int p = t & 1, pn = p ^ 1;

    for (int l = 0; l < 3; ++l) {
      // ---- per-(t,l) pointer resolution (uniform) ----
      const char *xhi, *xlo;
      int NCHX;
      if (l == 0) { xhi = base + EHI_B; xlo = base + ELO_B; NCHX = 33; }
      else {
        xhi = base + HS_B + (size_t)(((l - 1) * 2 + pn) * 2 + 0) * 524288u;
        xlo = base + HS_B + (size_t)(((l - 1) * 2 + pn) * 2 + 1) * 524288u;
        NCHX = 32;
      }
      const char* hhi = base + HS_B + (size_t)((l * 2 + p) * 2 + 0) * 524288u;
      const char* hlo = base + HS_B + (size_t)((l * 2 + p) * 2 + 1) * 524288u;
      const int wbase4 = (l == 0) ? 0 : (l == 1 ? 4 : 8);
      const char* wxhi = base + wOff[wbase4 + 0];
      const char* wxlo = base + wOff[wbase4 + 1];
      const char* whhi = base + wOff[wbase4 + 2];
      const char* whlo = base + wOff[wbase4 + 3];
      const float* bcomb = bcA + l * 4096;
      float* cbuf  = cbufA + (size_t)l * 262144;
      float* hdstf = hfA + (size_t)(l * 2 + pn) * 262144;
      unsigned short* hshi = (unsigned short*)(base + HS_B + (size_t)((l * 2 + pn) * 2 + 0) * 524288u);
      unsigned short* hslo = (unsigned short*)(base + HS_B + (size_t)((l * 2 + pn) * 2 + 1) * 524288u);

      const int nst = (NCHX > 32) ? NCHX : 32;
      const int sNch = sHalfW ? 32 : NCHX;
      const int waveNst = wHalf ? 32 : NCHX;

      // staging bases for this phase
      const char* sb0;
      {
        const char* t0;
        if (!sIsB) t0 = sHalfW ? (sPrec ? hlo : hhi) : (sPrec ? xlo : xhi);
        else       t0 = sHalfW ? (sPrec ? whlo : whhi) : (sPrec ? wxlo : wxhi);
        sb0 = t0 + (size_t)lane * 16;
      }
      const char* sb[4];
#pragma unroll
      for (int i = 0; i < 4; ++i) {
        int grp = sIsB ? (i * 64 + nt) : (mt * 4 + i);
        sb[i] = sb0 + (size_t)grp * sNch * 1024;
      }
      auto stage = [&](int s, int bufbase) {
        char* ldst = LBUF + bufbase + ldsoff0;
        const size_t so = (size_t)s * 1024;
#pragma unroll
        for (int i = 0; i < 4; ++i) gld16(sb[i] + so, ldst + i * 1024);
      };

      f32x4 accH[4], accL[4];
#pragma unroll
      for (int i = 0; i < 4; ++i) {
        accH[i] = f32x4{0.f, 0.f, 0.f, 0.f};
        accL[i] = f32x4{0.f, 0.f, 0.f, 0.f};
      }

      stage(0, 0);
      stage(1, 32768);

      for (int s = 0; s < nst; ++s) {
        const int bufb = (s & 1) << 15;
        if (s + 1 < sNch) { WAITV(4); }
        else              { WAITV(0); }
        BARRIER();

        if (s < waveNst) {
          const char* A0 = LBUF + bufb + (wHalf << 13);
          const char* B0 = LBUF + bufb + 16384 + (wHalf << 13);
          f16x8 ah[2], al[2], bh[2], bl[2];
#pragma unroll
          for (int r = 0; r < 2; ++r) {
            ah[r] = *(const f16x8*)(A0 + ((mb + r) << 10) + (lane << 4));
            al[r] = *(const f16x8*)(A0 + 4096 + ((mb + r) << 10) + (lane << 4));
          }
#pragma unroll
          for (int c = 0; c < 2; ++c) {
            bh[c] = *(const f16x8*)(B0 + ((nbb + c) << 10) + (lane << 4));
            bl[c] = *(const f16x8*)(B0 + 4096 + ((nbb + c) << 10) + (lane << 4));
          }
          __builtin_amdgcn_s_setprio(1);
#pragma unroll
          for (int r = 0; r < 2; ++r)
#pragma unroll
            for (int c = 0; c < 2; ++c) {
              int ix = r * 2 + c;
              accH[ix] = __builtin_amdgcn_mfma_f32_16x16x32_f16(ah[r], bh[c], accH[ix], 0, 0, 0);
              accL[ix] = __builtin_amdgcn_mfma_f32_16x16x32_f16(al[r], bh[c], accL[ix], 0, 0, 0);
              accL[ix] = __builtin_amdgcn_mfma_f32_16x16x32_f16(ah[r], bl[c], accL[ix], 0, 0, 0);
            }
          __builtin_amdgcn_s_setprio(0);
        }

        WAITLGKM0();
        BARRIER();
        if (s + 2 < sNch) stage(s + 2, bufb);
      }

      // ---- epilogue: combine halves in LDS, fused LSTM cell, split h emit ----
      BARRIER();
      float* GH = (float*)LBUF;            // [64][68]
      float* GL = GH + 64 * 68;
      if (wHalf == 0) {
#pragma unroll
        for (int r = 0; r < 2; ++r)
#pragma unroll
          for (int c = 0; c < 2; ++c) {
            f32x4 aH = accH[r * 2 + c], aL = accL[r * 2 + c];
            int mr = mrow0 + r * 16, nc = ncol0 + c * 16;
#pragma unroll
            for (int i = 0; i < 4; ++i) {
              GH[(mr + i) * 68 + nc] = aH[i];
              GL[(mr + i) * 68 + nc] = aL[i];
            }
          }
      }
      __syncthreads();
      if (wHalf == 1) {
#pragma unroll
        for (int r = 0; r < 2; ++r)
#pragma unroll
          for (int c = 0; c < 2; ++c) {
            f32x4 aH = accH[r * 2 + c], aL = accL[r * 2 + c];
            int mr = mrow0 + r * 16, nc = ncol0 + c * 16;
#pragma unroll
            for (int i = 0; i < 4; ++i) {
              GH[(mr + i) * 68 + nc] += aH[i];
              GL[(mr + i) * 68 + nc] += aL[i];
            }
          }
      }
      __syncthreads();

#pragma unroll
      for (int e = 0; e < 2; ++e) {
        int ci = tid * 2 + e;           // 0..1023
        int bl_ = ci >> 4, hh = ci & 15;
        int b = m0 + bl_, hcol = h0c + hh;
        float xi = GH[bl_ * 68 + hh]      + GL[bl_ * 68 + hh]      * LSC + bcomb[hcol];
        float xf = GH[bl_ * 68 + 16 + hh] + GL[bl_ * 68 + 16 + hh] * LSC + bcomb[1024 + hcol];
        float xg = GH[bl_ * 68 + 32 + hh] + GL[bl_ * 68 + 32 + hh] * LSC + bcomb[2048 + hcol];
        float xo = GH[bl_ * 68 + 48 + hh] + GL[bl_ * 68 + 48 + hh] * LSC + bcomb[3072 + hcol];
        size_t cidx = (size_t)b * 1024 + hcol;
        float cn = fsig(xf) * cbuf[cidx] + fsig(xi) * ftanhf(xg);
        float hn = fsig(xo) * ftanhf(cn);
        cbuf[cidx] = cn;
        hdstf[cidx] = hn;
        _Float16 h16 = (_Float16)hn;
        _Float16 l16 = (_Float16)((hn - (float)h16) * 2048.0f);
        size_t sa = slab_addr(b >> 4, 32, hcol, b & 15);
        hshi[sa] = f16b(h16);
        hslo[sa] = f16b(l16);
      }

      gbar(bar, bid);
    }

    // ---- decode phase: block bid handles batch row bid; 8-wave k-split ----
    {
      float* P = (float*)LBUF;             // [8][64]
      int* tokSp = (int*)(LBUF + 2048);
      const float* h2 = hfA + (size_t)(4 + pn) * 262144;
      const int b = bid;
      const float* hrow = h2 + (size_t)b * 1024 + wid * 128;
      float part = 0.f;
      if (lane < OO) {
        const float* wrow = Wdec + (size_t)lane * 1024 + wid * 128;
        float p0 = 0.f, p1 = 0.f, p2 = 0.f, p3 = 0.f;
        for (int k = 0; k < 128; k += 16) {
          float4 w0 = *(const float4*)(wrow + k);      float4 h0v = *(const float4*)(hrow + k);
          float4 w1 = *(const float4*)(wrow + k + 4);  float4 h1v = *(const float4*)(hrow + k + 4);
          float4 w2 = *(const float4*)(wrow + k + 8);  float4 h2v = *(const float4*)(hrow + k + 8);
          float4 w3 = *(const float4*)(wrow + k + 12); float4 h3v = *(const float4*)(hrow + k + 12);
          p0 += w0.x * h0v.x + w0.y * h0v.y + w0.z * h0v.z + w0.w * h0v.w;
          p1 += w1.x * h1v.x + w1.y * h1v.y + w1.z * h1v.z + w1.w * h1v.w;
          p2 += w2.x * h2v.x + w2.y * h2v.y + w2.z * h2v.z + w2.w * h2v.w;
          p3 += w3.x * h3v.x + w3.y * h3v.y + w3.z * h3v.z + w3.w * h3v.w;
        }
        part = (p0 + p1) + (p2 + p3);
      }
      P[wid * 64 + lane] = part;
      __syncthreads();
      if (wid == 0) {
        float logit = -3.0e38f;
        if (lane < OO) {
          logit = bdec[lane];
#pragma unroll
          for (int w = 0; w < 8; ++w) logit += P[w * 64 + lane];
        }
        float vv = logit;
        int idx = (lane < OO) ? lane : 1000;
#pragma unroll
        for (int m = 1; m < 64; m <<= 1) {
          float v2 = __shfl_xor(vv, m, 64);
          int i2 = __shfl_xor(idx, m, 64);
          if (v2 > vv || (v2 == vv && i2 < idx)) { vv = v2; idx = i2; }
        }
        if (lane < OO) out[(size_t)b * (TT * OO) + t * OO + lane] = logit;
        if (lane == 0) tokSp[0] = idx;
      }
      __syncthreads();
      if (t < TT - 1 && tid < 256) {
        int tok = tokSp[0];
        const float* erow = emb + (size_t)tok * 1024;
        float4 ev = ((const float4*)erow)[tid];
        float vals[4] = {ev.x, ev.y, ev.z, ev.w};
        unsigned short* ehi = (unsigned short*)(base + EHI_B);
        unsigned short* elo = (unsigned short*)(base + ELO_B);
#pragma unroll
        for (int r = 0; r < 4; ++r) {
          int j = tid * 4 + r;
          _Float16 h16 = (_Float16)vals[r];
          _Float16 l16 = (_Float16)((vals[r] - (float)h16) * 2048.0f);
          size_t a = slab_addr(b >> 4, 33, j, b & 15);
          ehi[a] = f16b(h16);
          elo[a] = f16b(l16);
        }
      }
      gbar(bar, bid);
    }
  }
}

// ---------------------------------------------------------------------------
__global__ void k_final(const float* __restrict__ hf, const float* __restrict__ cb,
                        float* __restrict__ out) {
  int i = blockIdx.x * blockDim.x + threadIdx.x;
  int stride = gridDim.x * blockDim.x;
  const int HBASE = BB * TT * OO;   // 1540096
  for (; i < 2 * 786432; i += stride) {
    if (i < 786432) {               // h [L][B][H]; final state in parity 0
      int l = i >> 18, r = i & 262143;
      out[HBASE + i] = hf[(size_t)(l * 2 + 0) * 262144 + r];
    } else {
      int j = i - 786432;
      out[HBASE + 786432 + j] = cb[j];
    }
  }
}

// ===========================================================================
// ==================== LEGACY (R4) FALLBACK PATH ============================
// ===========================================================================
#define O_EBUF  0
#define O_HPB   270336
#define O_CBUF  1843200
#define O_BCOMB 2629632
#define O_WSN   2641920
#define O_HP(l, p) (O_HPB + ((l) * 2 + (p)) * 262144)

__global__ void k_initO(float* ws, const float* __restrict__ props,
                        const float* __restrict__ emb,
                        const float* __restrict__ bih,
                        const float* __restrict__ bhh) {
  int i = blockIdx.x * blockDim.x + threadIdx.x;
  if (i < 270336) {
    int b = i / 1056, j = i % 1056;
    float v = 0.0f;
    if (j < 1024) v = emb[j];
    else if (j < 1028) v = props[b * 4 + (j - 1024)];
    ws[O_EBUF + i] = v;
  } else if (i < 270336 + 12288) {
    int j = i - 270336;
    ws[O_BCOMB + j] = bih[j] + bhh[j];
  }
}

__global__ __launch_bounds__(512, 2) void k_layerO(
    const float* __restrict__ xsrc, int xs, int Kx, int nst0,
    const float* __restrict__ hsrc,
    const float* __restrict__ Wx, int wxs,
    const float* __restrict__ Wh,
    const float* __restrict__ bcomb, float* __restrict__ cbuf,
    float* __restrict__ hdst) {
  __shared__ char LBUF[65536];
  const int tid = threadIdx.x;
  const int lane = tid & 63, wid = tid >> 6;
  const int sw = ((blockIdx.x & 7) << 5) + (blockIdx.x >> 3);
  const int mt = sw & 3, nt = sw >> 2;
  const int m0 = mt << 6, h0c = nt << 4;
  const int nstMax = (nst0 > 32) ? nst0 : 32;
  const int tile = tid >> 7;
  const int tt = tid & 127;
  const int srow = tt >> 1;
  const int kseg = (tt & 1) << 4;
  const int isB = tile >> 1, sHalf = tile & 1;
  const int myNst = sHalf ? 32 : nst0;
  const float* grow;
  int KactB = 0x7fffffff;
  if (!isB) {
    grow = sHalf ? (hsrc + (size_t)(m0 + srow) * 1024)
                 : (xsrc + (size_t)(m0 + srow) * xs);
  } else {
    int nrow = ((srow >> 4) << 10) + h0c + (srow & 15);
    grow = sHalf ? (Wh + (size_t)nrow * 1024) : (Wx + (size_t)nrow * wxs);
    KactB = sHalf ? 1024 : Kx;
  }
  const int wbase = ((srow >> 4) << 10) + ((tt & 1) << 9) + ((srow & 15) << 4);
  const int ssec = (isB << 14) + (sHalf << 13);
  const int wHalf = wid >> 2, q = wid & 3;
  const int mb = (q >> 1) << 1, nbb = (q & 1) << 1;
  const int waveNst = wHalf ? 32 : nst0;
  const int secAr = (wHalf << 13);
  const int secBr = 16384 + (wHalf << 13);
  f32x4 accH[4], accL[4];
#pragma unroll
  for (int i = 0; i < 4; ++i) {
    accH[i] = f32x4{0.f, 0.f, 0.f, 0.f};
    accL[i] = f32x4{0.f, 0.f, 0.f, 0.f};
  }
  float4 v[4];
  auto load_regs = [&](int s) {
    const int kl = (s << 5) + kseg;
    const float4* p = (const float4*)(grow + kl);
#pragma unroll
    for (int qq = 0; qq < 4; ++qq) {
      int kk = kl + qq * 4;
      if (kk < KactB) v[qq] = p[qq];
      else v[qq] = float4{0.f, 0.f, 0.f, 0.f};
    }
  };
  auto cvt_write = [&](int buf) {
    char* base = LBUF + buf * 32768 + ssec + wbase;
#pragma unroll
    for (int g = 0; g < 2; ++g) {
      float fs[8] = {v[2*g].x, v[2*g].y, v[2*g].z, v[2*g].w,
                     v[2*g+1].x, v[2*g+1].y, v[2*g+1].z, v[2*g+1].w};
      f16x8 hvv, lvv;
#pragma unroll
      for (int j = 0; j < 8; ++j) {
        _Float16 h16 = (_Float16)fs[j];
        lvv[j] = (_Float16)((fs[j] - (float)h16) * 2048.0f);
        hvv[j] = h16;
      }
      *(f16x8*)(base + g * 256) = hvv;
      *(f16x8*)(base + g * 256 + 4096) = lvv;
    }
  };
  load_regs(0);
  cvt_write(0);
  __syncthreads();
  for (int s = 0; s < nstMax; ++s) {
    const int cur = s & 1, nxt = cur ^ 1;
    const bool doStage = (s + 1 < myNst);
    if (doStage) load_regs(s + 1);
    if (s < waveNst) {
      const char* A0 = LBUF + cur * 32768 + secAr;
      const char* B0 = LBUF + cur * 32768 + secBr;
      f16x8 ah[2], al[2], bh[2], bl[2];
#pragma unroll
      for (int r = 0; r < 2; ++r) {
        ah[r] = *(const f16x8*)(A0 + ((mb + r) << 10) + (lane << 4));
        al[r] = *(const f16x8*)(A0 + 4096 + ((mb + r) << 10) + (lane << 4));
      }
#pragma unroll
      for (int c = 0; c < 2; ++c) {
        bh[c] = *(const f16x8*)(B0 + ((nbb + c) << 10) + (lane << 4));
        bl[c] = *(const f16x8*)(B0 + 4096 + ((nbb + c) << 10) + (lane << 4));
      }
#pragma unroll
      for (int r = 0; r < 2; ++r)
#pragma unroll
        for (int c = 0; c < 2; ++c) {
          int ix = r * 2 + c;
          accH[ix] = __builtin_amdgcn_mfma_f32_16x16x32_f16(ah[r], bh[c], accH[ix], 0, 0, 0);
          accL[ix] = __builtin_amdgcn_mfma_f32_16x16x32_f16(al[r], bh[c], accL[ix], 0, 0, 0);
          accL[ix] = __builtin_amdgcn_mfma_f32_16x16x32_f16(ah[r], bl[c], accL[ix], 0, 0, 0);
        }
    }
    if (doStage) cvt_write(nxt);
    __syncthreads();
  }
  float* GH = (float*)LBUF;
  float* GL = GH + 64 * 68;
  const int mrow0 = ((q >> 1) << 5) + ((lane >> 4) << 2);
  const int ncol0 = ((q & 1) << 5) + (lane & 15);
  if (wHalf == 0) {
#pragma unroll
    for (int r = 0; r < 2; ++r)
#pragma unroll
      for (int c = 0; c < 2; ++c) {
        f32x4 aHh = accH[r * 2 + c], aLl = accL[r * 2 + c];
        int mr = mrow0 + r * 16, nc = ncol0 + c * 16;
#pragma unroll
        for (int i = 0; i < 4; ++i) { GH[(mr + i) * 68 + nc] = aHh[i]; GL[(mr + i) * 68 + nc] = aLl[i]; }
      }
  }
  __syncthreads();
  if (wHalf == 1) {
#pragma unroll
    for (int r = 0; r < 2; ++r)
#pragma unroll
      for (int c = 0; c < 2; ++c) {
        f32x4 aHh = accH[r * 2 + c], aLl = accL[r * 2 + c];
        int mr = mrow0 + r * 16, nc = ncol0 + c * 16;
#pragma unroll
        for (int i = 0; i < 4; ++i) { GH[(mr + i) * 68 + nc] += aHh[i]; GL[(mr + i) * 68 + nc] += aLl[i]; }
      }
  }
  __syncthreads();
  const float LSC = 1.0f / 2048.0f;
#pragma unroll
  for (int e = 0; e < 2; ++e) {
    int ci = tid * 2 + e;
    int bl_ = ci >> 4, hh = ci & 15;
    int b = m0 + bl_, hcol = h0c + hh;
    float xi = GH[bl_ * 68 + hh]      + GL[bl_ * 68 + hh]      * LSC + bcomb[hcol];
    float xf = GH[bl_ * 68 + 16 + hh] + GL[bl_ * 68 + 16 + hh] * LSC + bcomb[1024 + hcol];
    float xg = GH[bl_ * 68 + 32 + hh] + GL[bl_ * 68 + 32 + hh] * LSC + bcomb[2048 + hcol];
    float xo = GH[bl_ * 68 + 48 + hh] + GL[bl_ * 68 + 48 + hh] * LSC + bcomb[3072 + hcol];
    size_t cidx = (size_t)b * 1024 + hcol;
    float cn = fsig(xf) * cbuf[cidx] + fsig(xi) * ftanhf(xg);
    float hn = fsig(xo) * ftanhf(cn);
    cbuf[cidx] = cn;
    hdst[cidx] = hn;
  }
}

__global__ __launch_bounds__(64) void k_decodeO(
    const float* __restrict__ h2, const float* __restrict__ Wdec,
    const float* __restrict__ bdec, const float* __restrict__ emb,
    float* __restrict__ out, float* __restrict__ ebuf, int t) {
  const int b = blockIdx.x, lane = threadIdx.x;
  const float* hrow = h2 + (size_t)b * 1024;
  float logit = 0.f;
  if (lane < OO) {
    const float* wrow = Wdec + (size_t)lane * 1024;
    float p0 = 0.f, p1 = 0.f, p2 = 0.f, p3 = 0.f;
    for (int k = 0; k < 1024; k += 16) {
      float4 w0 = *(const float4*)(wrow + k);      float4 h0v = *(const float4*)(hrow + k);
      float4 w1 = *(const float4*)(wrow + k + 4);  float4 h1v = *(const float4*)(hrow + k + 4);
      float4 w2 = *(const float4*)(wrow + k + 8);  float4 h2v = *(const float4*)(hrow + k + 8);
      float4 w3 = *(const float4*)(wrow + k + 12); float4 h3v = *(const float4*)(hrow + k + 12);
      p0 += w0.x * h0v.x + w0.y * h0v.y + w0.z * h0v.z + w0.w * h0v.w;
      p1 += w1.x * h1v.x + w1.y * h1v.y + w1.z * h1v.z + w1.w * h1v.w;
      p2 += w2.x * h2v.x + w2.y * h2v.y + w2.z * h2v.z + w2.w * h2v.w;
      p3 += w3.x * h3v.x + w3.y * h3v.y + w3.z * h3v.z + w3.w * h3v.w;
    }
    logit = ((p0 + p1) + (p2 + p3)) + bdec[lane];
  }
  float vv = (lane < OO) ? logit : -3.0e38f;
  int idx = (lane < OO) ? lane : 1000;
#pragma unroll
  for (int m = 1; m < 64; m <<= 1) {
    float v2 = __shfl_xor(vv, m, 64);
    int i2 = __shfl_xor(idx, m, 64);
    if (v2 > vv || (v2 == vv && i2 < idx)) { vv = v2; idx = i2; }
  }
  if (lane < OO) out[(size_t)b * (TT * OO) + t * OO + lane] = logit;
  if (t < TT - 1) {
    const float* erow = emb + (size_t)idx * 1024;
#pragma unroll
    for (int i = 0; i < 16; ++i) {
      int h = i * 64 + lane;
      ebuf[(size_t)b * 1056 + h] = erow[h];
    }
  }
}

__global__ void k_finalO(const float* __restrict__ ws, float* __restrict__ out) {
  int i = blockIdx.x * blockDim.x + threadIdx.x;
  int stride = gridDim.x * blockDim.x;
  const int HBASE = BB * TT * OO;
  for (; i < 2 * 786432; i += stride) {
    if (i < 786432) {
      int l = i >> 18, r = i & 262143;
      out[HBASE + i] = ws[O_HP(l, 0) + r];
    } else {
      int j = i - 786432;
      out[HBASE + 786432 + j] = ws[O_CBUF + j];
    }
  }
}

// ---------------------------------------------------------------------------
extern "C" void kernel_launch(void* const* d_in, const int* in_sizes, int n_in,
                              void* d_out, int out_size, void* d_ws, size_t ws_size,
                              hipStream_t stream) {
  const float* props = (const float*)d_in[1];
  const float* emb   = (const float*)d_in[2];
  const float* Wdec  = (const float*)d_in[3];
  const float* bdec  = (const float*)d_in[4];
  const float* Wih0  = (const float*)d_in[5];
  const float* Wihr  = (const float*)d_in[6];
  const float* Whh   = (const float*)d_in[7];
  const float* bih   = (const float*)d_in[8];
  const float* bhh   = (const float*)d_in[9];
  float* out = (float*)d_out;

  if (ws_size >= (size_t)WS_NEEDED) {
    // ---------------- mega-kernel path ----------------
    char* base = (char*)d_ws;
    float* cb = (float*)(base + CBUF_B);
    float* hf = (float*)(base + HF32_B);
    float* bc = (float*)(base + BCOMB_B);
    unsigned short* Ehi = (unsigned short*)(base + EHI_B);
    unsigned short* Elo = (unsigned short*)(base + ELO_B);
    unsigned* bar = (unsigned*)(base + BAR_B);
    unsigned short* Wp[12];
    {
      size_t off = W_B;
      Wp[0] = (unsigned short*)(base + off); off += 8650752u;   // Wx0 hi
      Wp[1] = (unsigned short*)(base + off); off += 8650752u;   // Wx0 lo
      for (int i = 2; i < 12; ++i) { Wp[i] = (unsigned short*)(base + off); off += 8388608u; }
      // 2,3=Wh0  4,5=Wx1  6,7=Wh1  8,9=Wx2  10,11=Wh2
    }

    k_zero<<<2048, 256, 0, stream>>>((float*)base, 2359296);          // cbuf+hf32
    k_zero<<<2048, 256, 0, stream>>>((float*)(base + HS_B), 1572864); // h split bufs
    k_binit<<<48, 256, 0, stream>>>(bc, bih, bhh, bar);
    k_einit<<<256, 256, 0, stream>>>(Ehi, Elo, emb, props);
    k_prepw<<<4096, 256, 0, stream>>>(Wih0, Wp[0], Wp[1], 1028, 33);
    k_prepw<<<4096, 256, 0, stream>>>(Whh,                           Wp[2], Wp[3], 1024, 32);
    k_prepw<<<4096, 256, 0, stream>>>(Wihr,                          Wp[4], Wp[5], 1024, 32);
    k_prepw<<<4096, 256, 0, stream>>>(Whh + (size_t)4096 * 1024,     Wp[6], Wp[7], 1024, 32);
    k_prepw<<<4096, 256, 0, stream>>>(Wihr + (size_t)4096 * 1024,    Wp[8], Wp[9], 1024, 32);
    k_prepw<<<4096, 256, 0, stream>>>(Whh + (size_t)2 * 4096 * 1024, Wp[10], Wp[11], 1024, 32);

    k_mega<<<256, 512, 0, stream>>>(base, Wdec, bdec, emb, out);

    k_final<<<2048, 256, 0, stream>>>(hf, cb, out);
  } else {
    // ---------------- legacy R4 path ----------------
    float* ws = (float*)d_ws;
    float* E  = ws + O_EBUF;
    float* cb = ws + O_CBUF;
    float* bc = ws + O_BCOMB;
    k_zero<<<2048, 256, 0, stream>>>(ws, O_WSN);
    k_initO<<<1104, 256, 0, stream>>>(ws, props, emb, bih, bhh);
    for (int t = 0; t < TT; ++t) {
      const int p = t & 1;
      k_layerO<<<256, 512, 0, stream>>>(E, 1056, 1028, 33, ws + O_HP(0, p),
                                        Wih0, 1028, Whh, bc, cb, ws + O_HP(0, p ^ 1));
      k_layerO<<<256, 512, 0, stream>>>(ws + O_HP(0, p ^ 1), 1024, 1024, 32,
                                        ws + O_HP(1, p), Wihr, 1024,
                                        Whh + (size_t)4096 * 1024,
                                        bc + 4096, cb + 262144, ws + O_HP(1, p ^ 1));
      k_layerO<<<256, 512, 0, stream>>>(ws + O_HP(1, p ^ 1), 1024, 1024, 32,
                                        ws + O_HP(2, p),
                                        Wihr + (size_t)4096 * 1024, 1024,
                                        Whh + (size_t)2 * 4096 * 1024,
                                        bc + 8192, cb + 524288, ws + O_HP(2, p ^ 1));
      k_decodeO<<<256, 64, 0, stream>>>(ws + O_HP(2, p ^ 1), Wdec, bdec, emb, out, E, t);
    }
    k_finalO<<<2048, 256, 0, stream>>>(ws, out);
  }
}

// Round 10
// 10084.199 us; speedup vs baseline: 2.3221x; 2.3221x over previous
//
#include <hip/hip_runtime.h>
#include <hip/hip_bf16.h>
#include <cstdint>
#include <cstddef>

// ---------------------------------------------------------------------------
// ConditionalSmilesRnn: 3-layer LSTM, H=1024, B=256, T=128, greedy decode.
// Round 10: R8 multi-launch structure with BK=64 chunks (half the barriers):
//   - 17/16 pipeline iterations per layer instead of 33/32
//   - LDS 2 x 64KB buffers; 8 gld16/wave/chunk (2KB contiguous per stream)
//   - counted vmcnt(8)/(0); setprio around MFMA clusters
//   - Wx0/E slab buffers padded to 34 k-chunks (even BK=64 split of K=1028+pad)
//   - ping-pong h buffers; legacy R4 fallback
// ---------------------------------------------------------------------------

#define BB 256
#define TT 128
#define OO 47

typedef __attribute__((ext_vector_type(8))) _Float16 f16x8;
typedef __attribute__((ext_vector_type(4))) float f32x4;

// ---- workspace byte offsets ----
#define CBUF_B   0u                    // [3][256][1024] f32
#define HF32_B   3145728u              // [3][2][256][1024] f32
#define BCOMB_B  9437184u              // [3][4096] f32
#define EHI_B    9486336u              // [16][34][512] f16 slabs (padded)
#define ELO_B    10043392u
#define HS_B     10600448u             // [3][2][2] x 524288 B
#define W_B      16891904u             // Wx0 hi/lo (34ch) + 10 x 8388608
#define WS_NEEDED 118603776u

#define BARRIER() asm volatile("s_barrier" ::: "memory")
#define WAITV(n)  asm volatile("s_waitcnt vmcnt(" #n ")" ::: "memory")
#define WAITLGKM0() asm volatile("s_waitcnt lgkmcnt(0)" ::: "memory")

__device__ __forceinline__ float fsig(float x) {
  return 1.0f / (1.0f + exp2f(-1.4426950408889634f * x));
}
__device__ __forceinline__ float ftanhf(float x) {
  float e = exp2f(2.8853900817779268f * x);
  return 1.0f - 2.0f / (e + 1.0f);
}
__device__ __forceinline__ unsigned short f16b(_Float16 h) {
  union { _Float16 f; unsigned short u; } c; c.f = h; return c.u;
}
__device__ __forceinline__ void gld16(const void* g, void* l) {
  __builtin_amdgcn_global_load_lds(
      (const __attribute__((address_space(1))) unsigned int*)g,
      (__attribute__((address_space(3))) unsigned int*)l, 16, 0, 0);
}
// slab address (f16 units) for element (k, r) of group grp; NCH = k-chunk stride
__device__ __forceinline__ size_t slab_addr(int grp, int NCH, int k, int r) {
  return ((size_t)grp * NCH + (k >> 5)) * 512 + ((k >> 4) & 1) * 256 +
         ((k >> 3) & 1) * 128 + r * 8 + (k & 7);
}

// ---------------------------------------------------------------------------
__global__ void k_zero(float* p, int n) {
  int i = blockIdx.x * blockDim.x + threadIdx.x;
  int stride = gridDim.x * blockDim.x;
  for (; i < n; i += stride) p[i] = 0.0f;
}

__global__ void k_binit(float* bc, const float* __restrict__ bih,
                        const float* __restrict__ bhh) {
  int i = blockIdx.x * blockDim.x + threadIdx.x;
  if (i < 12288) bc[i] = bih[i] + bhh[i];
}

// split fp32 weight matrix [4096][K] into slab-ordered f16 hi/lo (zero pad)
__global__ void k_prepw(const float* __restrict__ src, unsigned short* dhi,
                        unsigned short* dlo, int K, int NCH) {
  const int nrow = blockIdx.x;
  const int ngrp = nrow >> 4, rr = nrow & 15;
  const float* s = src + (size_t)nrow * K;
  for (int k = threadIdx.x; k < NCH * 32; k += blockDim.x) {
    float val = (k < K) ? s[k] : 0.0f;
    _Float16 h16 = (_Float16)val;
    _Float16 l16 = (_Float16)((val - (float)h16) * 2048.0f);
    size_t a = slab_addr(ngrp, NCH, k, rr);
    dhi[a] = f16b(h16);
    dlo[a] = f16b(l16);
  }
}

// E = [emb(tok 0) | props | pad] split into slabs (NCH=34, zero pad to 1088)
__global__ void k_einit(unsigned short* ehi, unsigned short* elo,
                        const float* __restrict__ emb,
                        const float* __restrict__ props) {
  const int b = blockIdx.x;
  for (int j = threadIdx.x; j < 1088; j += blockDim.x) {
    float val = (j < 1024) ? emb[j] : (j < 1028 ? props[b * 4 + (j - 1024)] : 0.0f);
    _Float16 h16 = (_Float16)val;
    _Float16 l16 = (_Float16)((val - (float)h16) * 2048.0f);
    size_t a = slab_addr(b >> 4, 34, j, b & 15);
    ehi[a] = f16b(h16);
    elo[a] = f16b(l16);
  }
}

// ---------------------------------------------------------------------------
// fp16x3 MFMA fused GEMM+LSTM cell, pre-split operands, BK=64 depth-2 pipeline.
// grid 256 (4 batch x 64 h tiles, XCD-swizzled), 512 threads (8 waves).
// LDS: 2 buffers x 64KB. Buffer: [isB<<15][half<<14][prec<<13][kc<<12][grp<<10].
// Staging: wave w -> isB=w>>2, half=(w>>1)&1, prec=w&1; 8 gld16/chunk.
// Compute: wave w -> wHalf=w>>2, quadrant q=w&3; 2 kc x 12 MFMA per chunk.
__global__ __launch_bounds__(512, 2) void k_layer(
    const char* __restrict__ xhi, const char* __restrict__ xlo,
    int NCHXmem, int nstX,
    const char* __restrict__ hhi, const char* __restrict__ hlo,
    const char* __restrict__ wxhi, const char* __restrict__ wxlo,
    const char* __restrict__ whhi, const char* __restrict__ whlo,
    const float* __restrict__ bcomb, float* __restrict__ cbuf,
    float* __restrict__ hdstf, unsigned short* __restrict__ hshi,
    unsigned short* __restrict__ hslo) {
  __shared__ char LBUF[131072];
  const int tid = threadIdx.x;
  const int lane = tid & 63, wid = tid >> 6;
  const int sw = ((blockIdx.x & 7) << 5) + (blockIdx.x >> 3);  // XCD swizzle
  const int mt = sw & 3, nt = sw >> 2;
  const int m0 = mt << 6, h0c = nt << 4;
  const int nst = (nstX > 16) ? nstX : 16;

  // ---- staging role ----
  const int sIsB = wid >> 2, sHalfW = (wid >> 1) & 1, sPrec = wid & 1;
  const int sNch = sHalfW ? 16 : nstX;            // chunk count (BK=64)
  const int sNmem = sHalfW ? 32 : NCHXmem;        // memory k-chunk stride
  const char* sbase[4];
  {
    const char* t0;
    if (!sIsB) t0 = sHalfW ? (sPrec ? hlo : hhi) : (sPrec ? xlo : xhi);
    else       t0 = sHalfW ? (sPrec ? whlo : whhi) : (sPrec ? wxlo : wxhi);
#pragma unroll
    for (int i = 0; i < 4; ++i) {
      int grp = sIsB ? (i * 64 + nt) : (mt * 4 + i);
      sbase[i] = t0 + (size_t)grp * sNmem * 1024 + (size_t)lane * 16;
    }
  }
  const int ldsoff0 = (sIsB << 15) + (sHalfW << 14) + (sPrec << 13);
  auto stage = [&](int s, int bufbase) {
    char* ldst = LBUF + bufbase + ldsoff0;
    const size_t so = (size_t)s * 2048;
#pragma unroll
    for (int i = 0; i < 4; ++i) {
      gld16(sbase[i] + so, ldst + (i << 10));
      gld16(sbase[i] + so + 1024, ldst + 4096 + (i << 10));
    }
  };

  // ---- compute role ----
  const int wHalf = wid >> 2, q = wid & 3;
  const int mb = (q >> 1) << 1, nbb = (q & 1) << 1;
  const int waveNst = wHalf ? 16 : nstX;

  f32x4 accH[4], accL[4];
#pragma unroll
  for (int i = 0; i < 4; ++i) {
    accH[i] = f32x4{0.f, 0.f, 0.f, 0.f};
    accL[i] = f32x4{0.f, 0.f, 0.f, 0.f};
  }

  // prologue: fill both buffers
  stage(0, 0);
  stage(1, 65536);

  for (int s = 0; s < nst; ++s) {
    const int bufb = (s & 1) << 16;
    if (s + 1 < sNch) { WAITV(8); }
    else              { WAITV(0); }
    BARRIER();

    if (s < waveNst) {
      const char* A0 = LBUF + bufb + (wHalf << 14);
      const char* B0 = LBUF + bufb + 32768 + (wHalf << 14);
#pragma unroll
      for (int kc = 0; kc < 2; ++kc) {
        const int kco = kc << 12;
        f16x8 ah[2], al[2], bh[2], bl[2];
#pragma unroll
        for (int r = 0; r < 2; ++r) {
          ah[r] = *(const f16x8*)(A0 + kco + ((mb + r) << 10) + (lane << 4));
          al[r] = *(const f16x8*)(A0 + 8192 + kco + ((mb + r) << 10) + (lane << 4));
        }
#pragma unroll
        for (int c = 0; c < 2; ++c) {
          bh[c] = *(const f16x8*)(B0 + kco + ((nbb + c) << 10) + (lane << 4));
          bl[c] = *(const f16x8*)(B0 + 8192 + kco + ((nbb + c) << 10) + (lane << 4));
        }
        __builtin_amdgcn_s_setprio(1);
#pragma unroll
        for (int r = 0; r < 2; ++r)
#pragma unroll
          for (int c = 0; c < 2; ++c) {
            int ix = r * 2 + c;
            accH[ix] = __builtin_amdgcn_mfma_f32_16x16x32_f16(ah[r], bh[c], accH[ix], 0, 0, 0);
            accL[ix] = __builtin_amdgcn_mfma_f32_16x16x32_f16(al[r], bh[c], accL[ix], 0, 0, 0);
            accL[ix] = __builtin_amdgcn_mfma_f32_16x16x32_f16(ah[r], bl[c], accL[ix], 0, 0, 0);
          }
        __builtin_amdgcn_s_setprio(0);
      }
    }

    WAITLGKM0();                     // this wave's ds_reads complete
    BARRIER();                       // all waves done reading buf
    if (s + 2 < sNch) stage(s + 2, bufb);   // refill freed buffer (async)
  }

  // ---- epilogue: combine halves, fused LSTM cell, split h emit ----
  BARRIER();
  float* GH = (float*)LBUF;            // [64][68]
  float* GL = GH + 64 * 68;
  const int mrow0 = ((q >> 1) << 5) + ((lane >> 4) << 2);
  const int ncol0 = ((q & 1) << 5) + (lane & 15);
  if (wHalf == 0) {
#pragma unroll
    for (int r = 0; r < 2; ++r)
#pragma unroll
      for (int c = 0; c < 2; ++c) {
        f32x4 aH = accH[r * 2 + c], aL = accL[r * 2 + c];
        int mr = mrow0 + r * 16, nc = ncol0 + c * 16;
#pragma unroll
        for (int i = 0; i < 4; ++i) {
          GH[(mr + i) * 68 + nc] = aH[i];
          GL[(mr + i) * 68 + nc] = aL[i];
        }
      }
  }
  __syncthreads();
  if (wHalf == 1) {
#pragma unroll
    for (int r = 0; r < 2; ++r)
#pragma unroll
      for (int c = 0; c < 2; ++c) {
        f32x4 aH = accH[r * 2 + c], aL = accL[r * 2 + c];
        int mr = mrow0 + r * 16, nc = ncol0 + c * 16;
#pragma unroll
        for (int i = 0; i < 4; ++i) {
          GH[(mr + i) * 68 + nc] += aH[i];
          GL[(mr + i) * 68 + nc] += aL[i];
        }
      }
  }
  __syncthreads();

  const float LSC = 1.0f / 2048.0f;
#pragma unroll
  for (int e = 0; e < 2; ++e) {
    int ci = tid * 2 + e;           // 0..1023
    int bl_ = ci >> 4, hh = ci & 15;
    int b = m0 + bl_, hcol = h0c + hh;
    float xi = GH[bl_ * 68 + hh]      + GL[bl_ * 68 + hh]      * LSC + bcomb[hcol];
    float xf = GH[bl_ * 68 + 16 + hh] + GL[bl_ * 68 + 16 + hh] * LSC + bcomb[1024 + hcol];
    float xg = GH[bl_ * 68 + 32 + hh] + GL[bl_ * 68 + 32 + hh] * LSC + bcomb[2048 + hcol];
    float xo = GH[bl_ * 68 + 48 + hh] + GL[bl_ * 68 + 48 + hh] * LSC + bcomb[3072 + hcol];
    size_t cidx = (size_t)b * 1024 + hcol;
    float cn = fsig(xf) * cbuf[cidx] + fsig(xi) * ftanhf(xg);
    float hn = fsig(xo) * ftanhf(cn);
    cbuf[cidx] = cn;
    hdstf[cidx] = hn;
    _Float16 h16 = (_Float16)hn;
    _Float16 l16 = (_Float16)((hn - (float)h16) * 2048.0f);
    size_t sa = slab_addr(b >> 4, 32, hcol, b & 15);
    hshi[sa] = f16b(h16);
    hslo[sa] = f16b(l16);
  }
}

// ---------------------------------------------------------------------------
// decode: 4-wave k-split dot, argmax, emit next-token emb into E slabs
__global__ __launch_bounds__(256) void k_decode(
    const float* __restrict__ h2, const float* __restrict__ Wdec,
    const float* __restrict__ bdec, const float* __restrict__ emb,
    float* __restrict__ out, unsigned short* __restrict__ ehi,
    unsigned short* __restrict__ elo, int t) {
  __shared__ float P[4][64];
  __shared__ int tokS;
  const int b = blockIdx.x;
  const int w = threadIdx.x >> 6, lane = threadIdx.x & 63;
  const float* hrow = h2 + (size_t)b * 1024 + w * 256;
  float part = 0.f;
  if (lane < OO) {
    const float* wrow = Wdec + (size_t)lane * 1024 + w * 256;
    float p0 = 0.f, p1 = 0.f, p2 = 0.f, p3 = 0.f;
    for (int k = 0; k < 256; k += 16) {
      float4 w0 = *(const float4*)(wrow + k);      float4 h0v = *(const float4*)(hrow + k);
      float4 w1 = *(const float4*)(wrow + k + 4);  float4 h1v = *(const float4*)(hrow + k + 4);
      float4 w2 = *(const float4*)(wrow + k + 8);  float4 h2v = *(const float4*)(hrow + k + 8);
      float4 w3 = *(const float4*)(wrow + k + 12); float4 h3v = *(const float4*)(hrow + k + 12);
      p0 += w0.x * h0v.x + w0.y * h0v.y + w0.z * h0v.z + w0.w * h0v.w;
      p1 += w1.x * h1v.x + w1.y * h1v.y + w1.z * h1v.z + w1.w * h1v.w;
      p2 += w2.x * h2v.x + w2.y * h2v.y + w2.z * h2v.z + w2.w * h2v.w;
      p3 += w3.x * h3v.x + w3.y * h3v.y + w3.z * h3v.z + w3.w * h3v.w;
    }
    part = (p0 + p1) + (p2 + p3);
  }
  P[w][lane] = part;
  __syncthreads();
  if (w == 0) {
    float logit = -3.0e38f;
    if (lane < OO)
      logit = P[0][lane] + P[1][lane] + P[2][lane] + P[3][lane] + bdec[lane];
    float vv = logit;
    int idx = (lane < OO) ? lane : 1000;
#pragma unroll
    for (int m = 1; m < 64; m <<= 1) {
      float v2 = __shfl_xor(vv, m, 64);
      int i2 = __shfl_xor(idx, m, 64);
      if (v2 > vv || (v2 == vv && i2 < idx)) { vv = v2; idx = i2; }
    }
    if (lane < OO) out[(size_t)b * (TT * OO) + t * OO + lane] = logit;
    if (lane == 0) tokS = idx;
  }
  __syncthreads();
  if (t < TT - 1) {
    const float* erow = emb + (size_t)tokS * 1024;
    float4 ev = ((const float4*)erow)[threadIdx.x];
    float vals[4] = {ev.x, ev.y, ev.z, ev.w};
#pragma unroll
    for (int r = 0; r < 4; ++r) {
      int j = threadIdx.x * 4 + r;
      _Float16 h16 = (_Float16)vals[r];
      _Float16 l16 = (_Float16)((vals[r] - (float)h16) * 2048.0f);
      size_t a = slab_addr(b >> 4, 34, j, b & 15);
      ehi[a] = f16b(h16);
      elo[a] = f16b(l16);
    }
  }
}

// ---------------------------------------------------------------------------
__global__ void k_final(const float* __restrict__ hf, const float* __restrict__ cb,
                        float* __restrict__ out) {
  int i = blockIdx.x * blockDim.x + threadIdx.x;
  int stride = gridDim.x * blockDim.x;
  const int HBASE = BB * TT * OO;   // 1540096
  for (; i < 2 * 786432; i += stride) {
    if (i < 786432) {               // h [L][B][H]; final state in parity 0
      int l = i >> 18, r = i & 262143;
      out[HBASE + i] = hf[(size_t)(l * 2 + 0) * 262144 + r];
    } else {
      int j = i - 786432;
      out[HBASE + 786432 + j] = cb[j];
    }
  }
}

// ===========================================================================
// ==================== LEGACY (R4) FALLBACK PATH ============================
// ===========================================================================
#define O_EBUF  0
#define O_HPB   270336
#define O_CBUF  1843200
#define O_BCOMB 2629632
#define O_WSN   2641920
#define O_HP(l, p) (O_HPB + ((l) * 2 + (p)) * 262144)

__global__ void k_initO(float* ws, const float* __restrict__ props,
                        const float* __restrict__ emb,
                        const float* __restrict__ bih,
                        const float* __restrict__ bhh) {
  int i = blockIdx.x * blockDim.x + threadIdx.x;
  if (i < 270336) {
    int b = i / 1056, j = i % 1056;
    float v = 0.0f;
    if (j < 1024) v = emb[j];
    else if (j < 1028) v = props[b * 4 + (j - 1024)];
    ws[O_EBUF + i] = v;
  } else if (i < 270336 + 12288) {
    int j = i - 270336;
    ws[O_BCOMB + j] = bih[j] + bhh[j];
  }
}

__global__ __launch_bounds__(512, 2) void k_layerO(
    const float* __restrict__ xsrc, int xs, int Kx, int nst0,
    const float* __restrict__ hsrc,
    const float* __restrict__ Wx, int wxs,
    const float* __restrict__ Wh,
    const float* __restrict__ bcomb, float* __restrict__ cbuf,
    float* __restrict__ hdst) {
  __shared__ char LBUF[65536];
  const int tid = threadIdx.x;
  const int lane = tid & 63, wid = tid >> 6;
  const int sw = ((blockIdx.x & 7) << 5) + (blockIdx.x >> 3);
  const int mt = sw & 3, nt = sw >> 2;
  const int m0 = mt << 6, h0c = nt << 4;
  const int nstMax = (nst0 > 32) ? nst0 : 32;
  const int tile = tid >> 7;
  const int tt = tid & 127;
  const int srow = tt >> 1;
  const int kseg = (tt & 1) << 4;
  const int isB = tile >> 1, sHalf = tile & 1;
  const int myNst = sHalf ? 32 : nst0;
  const float* grow;
  int KactB = 0x7fffffff;
  if (!isB) {
    grow = sHalf ? (hsrc + (size_t)(m0 + srow) * 1024)
                 : (xsrc + (size_t)(m0 + srow) * xs);
  } else {
    int nrow = ((srow >> 4) << 10) + h0c + (srow & 15);
    grow = sHalf ? (Wh + (size_t)nrow * 1024) : (Wx + (size_t)nrow * wxs);
    KactB = sHalf ? 1024 : Kx;
  }
  const int wbase = ((srow >> 4) << 10) + ((tt & 1) << 9) + ((srow & 15) << 4);
  const int ssec = (isB << 14) + (sHalf << 13);
  const int wHalf = wid >> 2, q = wid & 3;
  const int mb = (q >> 1) << 1, nbb = (q & 1) << 1;
  const int waveNst = wHalf ? 32 : nst0;
  const int secAr = (wHalf << 13);
  const int secBr = 16384 + (wHalf << 13);
  f32x4 accH[4], accL[4];
#pragma unroll
  for (int i = 0; i < 4; ++i) {
    accH[i] = f32x4{0.f, 0.f, 0.f, 0.f};
    accL[i] = f32x4{0.f, 0.f, 0.f, 0.f};
  }
  float4 v[4];
  auto load_regs = [&](int s) {
    const int kl = (s << 5) + kseg;
    const float4* p = (const float4*)(grow + kl);
#pragma unroll
    for (int qq = 0; qq < 4; ++qq) {
      int kk = kl + qq * 4;
      if (kk < KactB) v[qq] = p[qq];
      else v[qq] = float4{0.f, 0.f, 0.f, 0.f};
    }
  };
  auto cvt_write = [&](int buf) {
    char* base = LBUF + buf * 32768 + ssec + wbase;
#pragma unroll
    for (int g = 0; g < 2; ++g) {
      float fs[8] = {v[2*g].x, v[2*g].y, v[2*g].z, v[2*g].w,
                     v[2*g+1].x, v[2*g+1].y, v[2*g+1].z, v[2*g+1].w};
      f16x8 hvv, lvv;
#pragma unroll
      for (int j = 0; j < 8; ++j) {
        _Float16 h16 = (_Float16)fs[j];
        lvv[j] = (_Float16)((fs[j] - (float)h16) * 2048.0f);
        hvv[j] = h16;
      }
      *(f16x8*)(base + g * 256) = hvv;
      *(f16x8*)(base + g * 256 + 4096) = lvv;
    }
  };
  load_regs(0);
  cvt_write(0);
  __syncthreads();
  for (int s = 0; s < nstMax; ++s) {
    const int cur = s & 1, nxt = cur ^ 1;
    const bool doStage = (s + 1 < myNst);
    if (doStage) load_regs(s + 1);
    if (s < waveNst) {
      const char* A0 = LBUF + cur * 32768 + secAr;
      const char* B0 = LBUF + cur * 32768 + secBr;
      f16x8 ah[2], al[2], bh[2], bl[2];
#pragma unroll
      for (int r = 0; r < 2; ++r) {
        ah[r] = *(const f16x8*)(A0 + ((mb + r) << 10) + (lane << 4));
        al[r] = *(const f16x8*)(A0 + 4096 + ((mb + r) << 10) + (lane << 4));
      }
#pragma unroll
      for (int c = 0; c < 2; ++c) {
        bh[c] = *(const f16x8*)(B0 + ((nbb + c) << 10) + (lane << 4));
        bl[c] = *(const f16x8*)(B0 + 4096 + ((nbb + c) << 10) + (lane << 4));
      }
#pragma unroll
      for (int r = 0; r < 2; ++r)
#pragma unroll
        for (int c = 0; c < 2; ++c) {
          int ix = r * 2 + c;
          accH[ix] = __builtin_amdgcn_mfma_f32_16x16x32_f16(ah[r], bh[c], accH[ix], 0, 0, 0);
          accL[ix] = __builtin_amdgcn_mfma_f32_16x16x32_f16(al[r], bh[c], accL[ix], 0, 0, 0);
          accL[ix] = __builtin_amdgcn_mfma_f32_16x16x32_f16(ah[r], bl[c], accL[ix], 0, 0, 0);
        }
    }
    if (doStage) cvt_write(nxt);
    __syncthreads();
  }
  float* GH = (float*)LBUF;
  float* GL = GH + 64 * 68;
  const int mrow0 = ((q >> 1) << 5) + ((lane >> 4) << 2);
  const int ncol0 = ((q & 1) << 5) + (lane & 15);
  if (wHalf == 0) {
#pragma unroll
    for (int r = 0; r < 2; ++r)
#pragma unroll
      for (int c = 0; c < 2; ++c) {
        f32x4 aHh = accH[r * 2 + c], aLl = accL[r * 2 + c];
        int mr = mrow0 + r * 16, nc = ncol0 + c * 16;
#pragma unroll
        for (int i = 0; i < 4; ++i) { GH[(mr + i) * 68 + nc] = aHh[i]; GL[(mr + i) * 68 + nc] = aLl[i]; }
      }
  }
  __syncthreads();
  if (wHalf == 1) {
#pragma unroll
    for (int r = 0; r < 2; ++r)
#pragma unroll
      for (int c = 0; c < 2; ++c) {
        f32x4 aHh = accH[r * 2 + c], aLl = accL[r * 2 + c];
        int mr = mrow0 + r * 16, nc = ncol0 + c * 16;
#pragma unroll
        for (int i = 0; i < 4; ++i) { GH[(mr + i) * 68 + nc] += aHh[i]; GL[(mr + i) * 68 + nc] += aLl[i]; }
      }
  }
  __syncthreads();
  const float LSC = 1.0f / 2048.0f;
#pragma unroll
  for (int e = 0; e < 2; ++e) {
    int ci = tid * 2 + e;
    int bl_ = ci >> 4, hh = ci & 15;
    int b = m0 + bl_, hcol = h0c + hh;
    float xi = GH[bl_ * 68 + hh]      + GL[bl_ * 68 + hh]      * LSC + bcomb[hcol];
    float xf = GH[bl_ * 68 + 16 + hh] + GL[bl_ * 68 + 16 + hh] * LSC + bcomb[1024 + hcol];
    float xg = GH[bl_ * 68 + 32 + hh] + GL[bl_ * 68 + 32 + hh] * LSC + bcomb[2048 + hcol];
    float xo = GH[bl_ * 68 + 48 + hh] + GL[bl_ * 68 + 48 + hh] * LSC + bcomb[3072 + hcol];
    size_t cidx = (size_t)b * 1024 + hcol;
    float cn = fsig(xf) * cbuf[cidx] + fsig(xi) * ftanhf(xg);
    float hn = fsig(xo) * ftanhf(cn);
    cbuf[cidx] = cn;
    hdst[cidx] = hn;
  }
}

__global__ __launch_bounds__(64) void k_decodeO(
    const float* __restrict__ h2, const float* __restrict__ Wdec,
    const float* __restrict__ bdec, const float* __restrict__ emb,
    float* __restrict__ out, float* __restrict__ ebuf, int t) {
  const int b = blockIdx.x, lane = threadIdx.x;
  const float* hrow = h2 + (size_t)b * 1024;
  float logit = 0.f;
  if (lane < OO) {
    const float* wrow = Wdec + (size_t)lane * 1024;
    float p0 = 0.f, p1 = 0.f, p2 = 0.f, p3 = 0.f;
    for (int k = 0; k < 1024; k += 16) {
      float4 w0 = *(const float4*)(wrow + k);      float4 h0v = *(const float4*)(hrow + k);
      float4 w1 = *(const float4*)(wrow + k + 4);  float4 h1v = *(const float4*)(hrow + k + 4);
      float4 w2 = *(const float4*)(wrow + k + 8);  float4 h2v = *(const float4*)(hrow + k + 8);
      float4 w3 = *(const float4*)(wrow + k + 12); float4 h3v = *(const float4*)(hrow + k + 12);
      p0 += w0.x * h0v.x + w0.y * h0v.y + w0.z * h0v.z + w0.w * h0v.w;
      p1 += w1.x * h1v.x + w1.y * h1v.y + w1.z * h1v.z + w1.w * h1v.w;
      p2 += w2.x * h2v.x + w2.y * h2v.y + w2.z * h2v.z + w2.w * h2v.w;
      p3 += w3.x * h3v.x + w3.y * h3v.y + w3.z * h3v.z + w3.w * h3v.w;
    }
    logit = ((p0 + p1) + (p2 + p3)) + bdec[lane];
  }
  float vv = (lane < OO) ? logit : -3.0e38f;
  int idx = (lane < OO) ? lane : 1000;
#pragma unroll
  for (int m = 1; m < 64; m <<= 1) {
    float v2 = __shfl_xor(vv, m, 64);
    int i2 = __shfl_xor(idx, m, 64);
    if (v2 > vv || (v2 == vv && i2 < idx)) { vv = v2; idx = i2; }
  }
  if (lane < OO) out[(size_t)b * (TT * OO) + t * OO + lane] = logit;
  if (t < TT - 1) {
    const float* erow = emb + (size_t)idx * 1024;
#pragma unroll
    for (int i = 0; i < 16; ++i) {
      int h = i * 64 + lane;
      ebuf[(size_t)b * 1056 + h] = erow[h];
    }
  }
}

__global__ void k_finalO(const float* __restrict__ ws, float* __restrict__ out) {
  int i = blockIdx.x * blockDim.x + threadIdx.x;
  int stride = gridDim.x * blockDim.x;
  const int HBASE = BB * TT * OO;
  for (; i < 2 * 786432; i += stride) {
    if (i < 786432) {
      int l = i >> 18, r = i & 262143;
      out[HBASE + i] = ws[O_HP(l, 0) + r];
    } else {
      int j = i - 786432;
      out[HBASE + 786432 + j] = ws[O_CBUF + j];
    }
  }
}

// ---------------------------------------------------------------------------
extern "C" void kernel_launch(void* const* d_in, const int* in_sizes, int n_in,
                              void* d_out, int out_size, void* d_ws, size_t ws_size,
                              hipStream_t stream) {
  const float* props = (const float*)d_in[1];
  const float* emb   = (const float*)d_in[2];
  const float* Wdec  = (const float*)d_in[3];
  const float* bdec  = (const float*)d_in[4];
  const float* Wih0  = (const float*)d_in[5];
  const float* Wihr  = (const float*)d_in[6];
  const float* Whh   = (const float*)d_in[7];
  const float* bih   = (const float*)d_in[8];
  const float* bhh   = (const float*)d_in[9];
  float* out = (float*)d_out;

  if (ws_size >= (size_t)WS_NEEDED) {
    // ---------------- pre-split BK=64 path ----------------
    char* base = (char*)d_ws;
    float* cb = (float*)(base + CBUF_B);
    float* hf = (float*)(base + HF32_B);
    float* bc = (float*)(base + BCOMB_B);
    unsigned short* Ehi = (unsigned short*)(base + EHI_B);
    unsigned short* Elo = (unsigned short*)(base + ELO_B);
    auto HS = [&](int l, int p, int prec) {
      return (unsigned short*)(base + HS_B + (size_t)((l * 2 + p) * 2 + prec) * 524288u);
    };
    unsigned short* Wp[12];
    {
      size_t off = W_B;
      Wp[0] = (unsigned short*)(base + off); off += 8912896u;   // Wx0 hi (34ch)
      Wp[1] = (unsigned short*)(base + off); off += 8912896u;   // Wx0 lo
      for (int i = 2; i < 12; ++i) { Wp[i] = (unsigned short*)(base + off); off += 8388608u; }
      // 2,3=Wh0  4,5=Wx1  6,7=Wh1  8,9=Wx2  10,11=Wh2
    }

    k_zero<<<2048, 256, 0, stream>>>((float*)base, 2359296);          // cbuf+hf32
    k_zero<<<2048, 256, 0, stream>>>((float*)(base + HS_B), 1572864); // h split bufs
    k_binit<<<48, 256, 0, stream>>>(bc, bih, bhh);
    k_einit<<<256, 256, 0, stream>>>(Ehi, Elo, emb, props);
    k_prepw<<<4096, 256, 0, stream>>>(Wih0, Wp[0], Wp[1], 1028, 34);
    k_prepw<<<4096, 256, 0, stream>>>(Whh,                           Wp[2], Wp[3], 1024, 32);
    k_prepw<<<4096, 256, 0, stream>>>(Wihr,                          Wp[4], Wp[5], 1024, 32);
    k_prepw<<<4096, 256, 0, stream>>>(Whh + (size_t)4096 * 1024,     Wp[6], Wp[7], 1024, 32);
    k_prepw<<<4096, 256, 0, stream>>>(Wihr + (size_t)4096 * 1024,    Wp[8], Wp[9], 1024, 32);
    k_prepw<<<4096, 256, 0, stream>>>(Whh + (size_t)2 * 4096 * 1024, Wp[10], Wp[11], 1024, 32);

    for (int t = 0; t < TT; ++t) {
      const int p = t & 1, pn = p ^ 1;
      k_layer<<<256, 512, 0, stream>>>(
          (const char*)Ehi, (const char*)Elo, 34, 17,
          (const char*)HS(0, p, 0), (const char*)HS(0, p, 1),
          (const char*)Wp[0], (const char*)Wp[1],
          (const char*)Wp[2], (const char*)Wp[3],
          bc, cb, hf + (size_t)(0 * 2 + pn) * 262144,
          HS(0, pn, 0), HS(0, pn, 1));
      k_layer<<<256, 512, 0, stream>>>(
          (const char*)HS(0, pn, 0), (const char*)HS(0, pn, 1), 32, 16,
          (const char*)HS(1, p, 0), (const char*)HS(1, p, 1),
          (const char*)Wp[4], (const char*)Wp[5],
          (const char*)Wp[6], (const char*)Wp[7],
          bc + 4096, cb + 262144, hf + (size_t)(1 * 2 + pn) * 262144,
          HS(1, pn, 0), HS(1, pn, 1));
      k_layer<<<256, 512, 0, stream>>>(
          (const char*)HS(1, pn, 0), (const char*)HS(1, pn, 1), 32, 16,
          (const char*)HS(2, p, 0), (const char*)HS(2, p, 1),
          (const char*)Wp[8], (const char*)Wp[9],
          (const char*)Wp[10], (const char*)Wp[11],
          bc + 8192, cb + 524288, hf + (size_t)(2 * 2 + pn) * 262144,
          HS(2, pn, 0), HS(2, pn, 1));
      k_decode<<<256, 256, 0, stream>>>(hf + (size_t)(2 * 2 + pn) * 262144,
                                        Wdec, bdec, emb, out, Ehi, Elo, t);
    }
    k_final<<<2048, 256, 0, stream>>>(hf, cb, out);
  } else {
    // ---------------- legacy R4 path ----------------
    float* ws = (float*)d_ws;
    float* E  = ws + O_EBUF;
    float* cb = ws + O_CBUF;
    float* bc = ws + O_BCOMB;
    k_zero<<<2048, 256, 0, stream>>>(ws, O_WSN);
    k_initO<<<1104, 256, 0, stream>>>(ws, props, emb, bih, bhh);
    for (int t = 0; t < TT; ++t) {
      const int p = t & 1;
      k_layerO<<<256, 512, 0, stream>>>(E, 1056, 1028, 33, ws + O_HP(0, p),
                                        Wih0, 1028, Whh, bc, cb, ws + O_HP(0, p ^ 1));
      k_layerO<<<256, 512, 0, stream>>>(ws + O_HP(0, p ^ 1), 1024, 1024, 32,
                                        ws + O_HP(1, p), Wihr, 1024,
                                        Whh + (size_t)4096 * 1024,
                                        bc + 4096, cb + 262144, ws + O_HP(1, p ^ 1));
      k_layerO<<<256, 512, 0, stream>>>(ws + O_HP(1, p ^ 1), 1024, 1024, 32,
                                        ws + O_HP(2, p),
                                        Wihr + (size_t)4096 * 1024, 1024,
                                        Whh + (size_t)2 * 4096 * 1024,
                                        bc + 8192, cb + 524288, ws + O_HP(2, p ^ 1));
      k_decodeO<<<256, 64, 0, stream>>>(ws + O_HP(2, p ^ 1), Wdec, bdec, emb, out, E, t);
    }
    k_finalO<<<2048, 256, 0, stream>>>(ws, out);
  }
}

// Round 12
// 9954.124 us; speedup vs baseline: 2.3524x; 1.0131x over previous
//
#include <hip/hip_runtime.h>
#include <hip/hip_bf16.h>
#include <cstdint>
#include <cstddef>

// ---------------------------------------------------------------------------
// ConditionalSmilesRnn: 3-layer LSTM, H=1024, B=256, T=128, greedy decode.
// Round 12: R10 (best-known-good) with the block->XCD mapping FIXED:
//   blockIdx = mt*64 + nt  (NO swizzle) so the 4 mt-blocks sharing each
//   nt's weight slice land on the SAME XCD (bid%8 == nt%8) and share L2.
//   (R9 counters showed full weight set streaming from HBM every step; the
//   old swizzle spread weight-sharing blocks across 4 XCDs.)
//   - BK=64, depth-2 counted-vmcnt pipeline, setprio, pre-split fp16x3
//   - ping-pong h buffers; legacy R4 fallback
// ---------------------------------------------------------------------------

#define BB 256
#define TT 128
#define OO 47

typedef __attribute__((ext_vector_type(8))) _Float16 f16x8;
typedef __attribute__((ext_vector_type(4))) float f32x4;

// ---- workspace byte offsets ----
#define CBUF_B   0u                    // [3][256][1024] f32
#define HF32_B   3145728u              // [3][2][256][1024] f32
#define BCOMB_B  9437184u              // [3][4096] f32
#define EHI_B    9486336u              // [16][34][512] f16 slabs (padded)
#define ELO_B    10043392u
#define HS_B     10600448u             // [3][2][2] x 524288 B
#define W_B      16891904u             // Wx0 hi/lo (34ch) + 10 x 8388608
#define WS_NEEDED 118603776u

#define BARRIER() asm volatile("s_barrier" ::: "memory")
#define WAITV(n)  asm volatile("s_waitcnt vmcnt(" #n ")" ::: "memory")
#define WAITLGKM0() asm volatile("s_waitcnt lgkmcnt(0)" ::: "memory")

__device__ __forceinline__ float fsig(float x) {
  return 1.0f / (1.0f + exp2f(-1.4426950408889634f * x));
}
__device__ __forceinline__ float ftanhf(float x) {
  float e = exp2f(2.8853900817779268f * x);
  return 1.0f - 2.0f / (e + 1.0f);
}
__device__ __forceinline__ unsigned short f16b(_Float16 h) {
  union { _Float16 f; unsigned short u; } c; c.f = h; return c.u;
}
__device__ __forceinline__ void gld16(const void* g, void* l) {
  __builtin_amdgcn_global_load_lds(
      (const __attribute__((address_space(1))) unsigned int*)g,
      (__attribute__((address_space(3))) unsigned int*)l, 16, 0, 0);
}
// slab address (f16 units) for element (k, r) of group grp; NCH = k-chunk stride
__device__ __forceinline__ size_t slab_addr(int grp, int NCH, int k, int r) {
  return ((size_t)grp * NCH + (k >> 5)) * 512 + ((k >> 4) & 1) * 256 +
         ((k >> 3) & 1) * 128 + r * 8 + (k & 7);
}

// ---------------------------------------------------------------------------
__global__ void k_zero(float* p, int n) {
  int i = blockIdx.x * blockDim.x + threadIdx.x;
  int stride = gridDim.x * blockDim.x;
  for (; i < n; i += stride) p[i] = 0.0f;
}

__global__ void k_binit(float* bc, const float* __restrict__ bih,
                        const float* __restrict__ bhh) {
  int i = blockIdx.x * blockDim.x + threadIdx.x;
  if (i < 12288) bc[i] = bih[i] + bhh[i];
}

// split fp32 weight matrix [4096][K] into slab-ordered f16 hi/lo (zero pad)
__global__ void k_prepw(const float* __restrict__ src, unsigned short* dhi,
                        unsigned short* dlo, int K, int NCH) {
  const int nrow = blockIdx.x;
  const int ngrp = nrow >> 4, rr = nrow & 15;
  const float* s = src + (size_t)nrow * K;
  for (int k = threadIdx.x; k < NCH * 32; k += blockDim.x) {
    float val = (k < K) ? s[k] : 0.0f;
    _Float16 h16 = (_Float16)val;
    _Float16 l16 = (_Float16)((val - (float)h16) * 2048.0f);
    size_t a = slab_addr(ngrp, NCH, k, rr);
    dhi[a] = f16b(h16);
    dlo[a] = f16b(l16);
  }
}

// E = [emb(tok 0) | props | pad] split into slabs (NCH=34, zero pad to 1088)
__global__ void k_einit(unsigned short* ehi, unsigned short* elo,
                        const float* __restrict__ emb,
                        const float* __restrict__ props) {
  const int b = blockIdx.x;
  for (int j = threadIdx.x; j < 1088; j += blockDim.x) {
    float val = (j < 1024) ? emb[j] : (j < 1028 ? props[b * 4 + (j - 1024)] : 0.0f);
    _Float16 h16 = (_Float16)val;
    _Float16 l16 = (_Float16)((val - (float)h16) * 2048.0f);
    size_t a = slab_addr(b >> 4, 34, j, b & 15);
    ehi[a] = f16b(h16);
    elo[a] = f16b(l16);
  }
}

// ---------------------------------------------------------------------------
// fp16x3 MFMA fused GEMM+LSTM cell, pre-split operands, BK=64 depth-2 pipeline.
// grid 256: bid = mt*64 + nt  ->  the 4 mt-blocks of one nt share an XCD.
// 512 threads (8 waves). LDS: 2 buffers x 64KB.
// Buffer: [isB<<15][half<<14][prec<<13][kc<<12][grp<<10].
// Staging: wave w -> isB=w>>2, half=(w>>1)&1, prec=w&1; 8 gld16/chunk.
// Compute: wave w -> wHalf=w>>2, quadrant q=w&3; 2 kc x 12 MFMA per chunk.
__global__ __launch_bounds__(512, 2) void k_layer(
    const char* __restrict__ xhi, const char* __restrict__ xlo,
    int NCHXmem, int nstX,
    const char* __restrict__ hhi, const char* __restrict__ hlo,
    const char* __restrict__ wxhi, const char* __restrict__ wxlo,
    const char* __restrict__ whhi, const char* __restrict__ whlo,
    const float* __restrict__ bcomb, float* __restrict__ cbuf,
    float* __restrict__ hdstf, unsigned short* __restrict__ hshi,
    unsigned short* __restrict__ hslo) {
  __shared__ char LBUF[131072];
  const int tid = threadIdx.x;
  const int lane = tid & 63, wid = tid >> 6;
  const int nt = blockIdx.x & 63;           // XCD-co-located weight sharers
  const int mt = blockIdx.x >> 6;
  const int m0 = mt << 6, h0c = nt << 4;
  const int nst = (nstX > 16) ? nstX : 16;

  // ---- staging role ----
  const int sIsB = wid >> 2, sHalfW = (wid >> 1) & 1, sPrec = wid & 1;
  const int sNch = sHalfW ? 16 : nstX;            // chunk count (BK=64)
  const int sNmem = sHalfW ? 32 : NCHXmem;        // memory k-chunk stride
  const char* sbase[4];
  {
    const char* t0;
    if (!sIsB) t0 = sHalfW ? (sPrec ? hlo : hhi) : (sPrec ? xlo : xhi);
    else       t0 = sHalfW ? (sPrec ? whlo : whhi) : (sPrec ? wxlo : wxhi);
#pragma unroll
    for (int i = 0; i < 4; ++i) {
      int grp = sIsB ? (i * 64 + nt) : (mt * 4 + i);
      sbase[i] = t0 + (size_t)grp * sNmem * 1024 + (size_t)lane * 16;
    }
  }
  const int ldsoff0 = (sIsB << 15) + (sHalfW << 14) + (sPrec << 13);
  auto stage = [&](int s, int bufbase) {
    char* ldst = LBUF + bufbase + ldsoff0;
    const size_t so = (size_t)s * 2048;
#pragma unroll
    for (int i = 0; i < 4; ++i) {
      gld16(sbase[i] + so, ldst + (i << 10));
      gld16(sbase[i] + so + 1024, ldst + 4096 + (i << 10));
    }
  };

  // ---- compute role ----
  const int wHalf = wid >> 2, q = wid & 3;
  const int mb = (q >> 1) << 1, nbb = (q & 1) << 1;
  const int waveNst = wHalf ? 16 : nstX;

  f32x4 accH[4], accL[4];
#pragma unroll
  for (int i = 0; i < 4; ++i) {
    accH[i] = f32x4{0.f, 0.f, 0.f, 0.f};
    accL[i] = f32x4{0.f, 0.f, 0.f, 0.f};
  }

  // prologue: fill both buffers
  stage(0, 0);
  stage(1, 65536);

  for (int s = 0; s < nst; ++s) {
    const int bufb = (s & 1) << 16;
    if (s + 1 < sNch) { WAITV(8); }
    else              { WAITV(0); }
    BARRIER();

    if (s < waveNst) {
      const char* A0 = LBUF + bufb + (wHalf << 14);
      const char* B0 = LBUF + bufb + 32768 + (wHalf << 14);
#pragma unroll
      for (int kc = 0; kc < 2; ++kc) {
        const int kco = kc << 12;
        f16x8 ah[2], al[2], bh[2], bl[2];
#pragma unroll
        for (int r = 0; r < 2; ++r) {
          ah[r] = *(const f16x8*)(A0 + kco + ((mb + r) << 10) + (lane << 4));
          al[r] = *(const f16x8*)(A0 + 8192 + kco + ((mb + r) << 10) + (lane << 4));
        }
#pragma unroll
        for (int c = 0; c < 2; ++c) {
          bh[c] = *(const f16x8*)(B0 + kco + ((nbb + c) << 10) + (lane << 4));
          bl[c] = *(const f16x8*)(B0 + 8192 + kco + ((nbb + c) << 10) + (lane << 4));
        }
        __builtin_amdgcn_s_setprio(1);
#pragma unroll
        for (int r = 0; r < 2; ++r)
#pragma unroll
          for (int c = 0; c < 2; ++c) {
            int ix = r * 2 + c;
            accH[ix] = __builtin_amdgcn_mfma_f32_16x16x32_f16(ah[r], bh[c], accH[ix], 0, 0, 0);
            accL[ix] = __builtin_amdgcn_mfma_f32_16x16x32_f16(al[r], bh[c], accL[ix], 0, 0, 0);
            accL[ix] = __builtin_amdgcn_mfma_f32_16x16x32_f16(ah[r], bl[c], accL[ix], 0, 0, 0);
          }
        __builtin_amdgcn_s_setprio(0);
      }
    }

    WAITLGKM0();                     // this wave's ds_reads complete
    BARRIER();                       // all waves done reading buf
    if (s + 2 < sNch) stage(s + 2, bufb);   // refill freed buffer (async)
  }

  // ---- epilogue: combine halves, fused LSTM cell, split h emit ----
  BARRIER();
  float* GH = (float*)LBUF;            // [64][68]
  float* GL = GH + 64 * 68;
  const int mrow0 = ((q >> 1) << 5) + ((lane >> 4) << 2);
  const int ncol0 = ((q & 1) << 5) + (lane & 15);
  if (wHalf == 0) {
#pragma unroll
    for (int r = 0; r < 2; ++r)
#pragma unroll
      for (int c = 0; c < 2; ++c) {
        f32x4 aH = accH[r * 2 + c], aL = accL[r * 2 + c];
        int mr = mrow0 + r * 16, nc = ncol0 + c * 16;
#pragma unroll
        for (int i = 0; i < 4; ++i) {
          GH[(mr + i) * 68 + nc] = aH[i];
          GL[(mr + i) * 68 + nc] = aL[i];
        }
      }
  }
  __syncthreads();
  if (wHalf == 1) {
#pragma unroll
    for (int r = 0; r < 2; ++r)
#pragma unroll
      for (int c = 0; c < 2; ++c) {
        f32x4 aH = accH[r * 2 + c], aL = accL[r * 2 + c];
        int mr = mrow0 + r * 16, nc = ncol0 + c * 16;
#pragma unroll
        for (int i = 0; i < 4; ++i) {
          GH[(mr + i) * 68 + nc] += aH[i];
          GL[(mr + i) * 68 + nc] += aL[i];
        }
      }
  }
  __syncthreads();

  const float LSC = 1.0f / 2048.0f;
#pragma unroll
  for (int e = 0; e < 2; ++e) {
    int ci = tid * 2 + e;           // 0..1023
    int bl_ = ci >> 4, hh = ci & 15;
    int b = m0 + bl_, hcol = h0c + hh;
    float xi = GH[bl_ * 68 + hh]      + GL[bl_ * 68 + hh]      * LSC + bcomb[hcol];
    float xf = GH[bl_ * 68 + 16 + hh] + GL[bl_ * 68 + 16 + hh] * LSC + bcomb[1024 + hcol];
    float xg = GH[bl_ * 68 + 32 + hh] + GL[bl_ * 68 + 32 + hh] * LSC + bcomb[2048 + hcol];
    float xo = GH[bl_ * 68 + 48 + hh] + GL[bl_ * 68 + 48 + hh] * LSC + bcomb[3072 + hcol];
    size_t cidx = (size_t)b * 1024 + hcol;
    float cn = fsig(xf) * cbuf[cidx] + fsig(xi) * ftanhf(xg);
    float hn = fsig(xo) * ftanhf(cn);
    cbuf[cidx] = cn;
    hdstf[cidx] = hn;
    _Float16 h16 = (_Float16)hn;
    _Float16 l16 = (_Float16)((hn - (float)h16) * 2048.0f);
    size_t sa = slab_addr(b >> 4, 32, hcol, b & 15);
    hshi[sa] = f16b(h16);
    hslo[sa] = f16b(l16);
  }
}

// ---------------------------------------------------------------------------
// decode: 4-wave k-split dot, argmax, emit next-token emb into E slabs
__global__ __launch_bounds__(256) void k_decode(
    const float* __restrict__ h2, const float* __restrict__ Wdec,
    const float* __restrict__ bdec, const float* __restrict__ emb,
    float* __restrict__ out, unsigned short* __restrict__ ehi,
    unsigned short* __restrict__ elo, int t) {
  __shared__ float P[4][64];
  __shared__ int tokS;
  const int b = blockIdx.x;
  const int w = threadIdx.x >> 6, lane = threadIdx.x & 63;
  const float* hrow = h2 + (size_t)b * 1024 + w * 256;
  float part = 0.f;
  if (lane < OO) {
    const float* wrow = Wdec + (size_t)lane * 1024 + w * 256;
    float p0 = 0.f, p1 = 0.f, p2 = 0.f, p3 = 0.f;
    for (int k = 0; k < 256; k += 16) {
      float4 w0 = *(const float4*)(wrow + k);      float4 h0v = *(const float4*)(hrow + k);
      float4 w1 = *(const float4*)(wrow + k + 4);  float4 h1v = *(const float4*)(hrow + k + 4);
      float4 w2 = *(const float4*)(wrow + k + 8);  float4 h2v = *(const float4*)(hrow + k + 8);
      float4 w3 = *(const float4*)(wrow + k + 12); float4 h3v = *(const float4*)(hrow + k + 12);
      p0 += w0.x * h0v.x + w0.y * h0v.y + w0.z * h0v.z + w0.w * h0v.w;
      p1 += w1.x * h1v.x + w1.y * h1v.y + w1.z * h1v.z + w1.w * h1v.w;
      p2 += w2.x * h2v.x + w2.y * h2v.y + w2.z * h2v.z + w2.w * h2v.w;
      p3 += w3.x * h3v.x + w3.y * h3v.y + w3.z * h3v.z + w3.w * h3v.w;
    }
    part = (p0 + p1) + (p2 + p3);
  }
  P[w][lane] = part;
  __syncthreads();
  if (w == 0) {
    float logit = -3.0e38f;
    if (lane < OO)
      logit = P[0][lane] + P[1][lane] + P[2][lane] + P[3][lane] + bdec[lane];
    float vv = logit;
    int idx = (lane < OO) ? lane : 1000;
#pragma unroll
    for (int m = 1; m < 64; m <<= 1) {
      float v2 = __shfl_xor(vv, m, 64);
      int i2 = __shfl_xor(idx, m, 64);
      if (v2 > vv || (v2 == vv && i2 < idx)) { vv = v2; idx = i2; }
    }
    if (lane < OO) out[(size_t)b * (TT * OO) + t * OO + lane] = logit;
    if (lane == 0) tokS = idx;
  }
  __syncthreads();
  if (t < TT - 1) {
    const float* erow = emb + (size_t)tokS * 1024;
    float4 ev = ((const float4*)erow)[threadIdx.x];
    float vals[4] = {ev.x, ev.y, ev.z, ev.w};
#pragma unroll
    for (int r = 0; r < 4; ++r) {
      int j = threadIdx.x * 4 + r;
      _Float16 h16 = (_Float16)vals[r];
      _Float16 l16 = (_Float16)((vals[r] - (float)h16) * 2048.0f);
      size_t a = slab_addr(b >> 4, 34, j, b & 15);
      ehi[a] = f16b(h16);
      elo[a] = f16b(l16);
    }
  }
}

// ---------------------------------------------------------------------------
__global__ void k_final(const float* __restrict__ hf, const float* __restrict__ cb,
                        float* __restrict__ out) {
  int i = blockIdx.x * blockDim.x + threadIdx.x;
  int stride = gridDim.x * blockDim.x;
  const int HBASE = BB * TT * OO;   // 1540096
  for (; i < 2 * 786432; i += stride) {
    if (i < 786432) {               // h [L][B][H]; final state in parity 0
      int l = i >> 18, r = i & 262143;
      out[HBASE + i] = hf[(size_t)(l * 2 + 0) * 262144 + r];
    } else {
      int j = i - 786432;
      out[HBASE + 786432 + j] = cb[j];
    }
  }
}

// ===========================================================================
// ==================== LEGACY (R4) FALLBACK PATH ============================
// ===========================================================================
#define O_EBUF  0
#define O_HPB   270336
#define O_CBUF  1843200
#define O_BCOMB 2629632
#define O_WSN   2641920
#define O_HP(l, p) (O_HPB + ((l) * 2 + (p)) * 262144)

__global__ void k_initO(float* ws, const float* __restrict__ props,
                        const float* __restrict__ emb,
                        const float* __restrict__ bih,
                        const float* __restrict__ bhh) {
  int i = blockIdx.x * blockDim.x + threadIdx.x;
  if (i < 270336) {
    int b = i / 1056, j = i % 1056;
    float v = 0.0f;
    if (j < 1024) v = emb[j];
    else if (j < 1028) v = props[b * 4 + (j - 1024)];
    ws[O_EBUF + i] = v;
  } else if (i < 270336 + 12288) {
    int j = i - 270336;
    ws[O_BCOMB + j] = bih[j] + bhh[j];
  }
}

__global__ __launch_bounds__(512, 2) void k_layerO(
    const float* __restrict__ xsrc, int xs, int Kx, int nst0,
    const float* __restrict__ hsrc,
    const float* __restrict__ Wx, int wxs,
    const float* __restrict__ Wh,
    const float* __restrict__ bcomb, float* __restrict__ cbuf,
    float* __restrict__ hdst) {
  __shared__ char LBUF[65536];
  const int tid = threadIdx.x;
  const int lane = tid & 63, wid = tid >> 6;
  const int sw = ((blockIdx.x & 7) << 5) + (blockIdx.x >> 3);
  const int mt = sw & 3, nt = sw >> 2;
  const int m0 = mt << 6, h0c = nt << 4;
  const int nstMax = (nst0 > 32) ? nst0 : 32;
  const int tile = tid >> 7;
  const int tt = tid & 127;
  const int srow = tt >> 1;
  const int kseg = (tt & 1) << 4;
  const int isB = tile >> 1, sHalf = tile & 1;
  const int myNst = sHalf ? 32 : nst0;
  const float* grow;
  int KactB = 0x7fffffff;
  if (!isB) {
    grow = sHalf ? (hsrc + (size_t)(m0 + srow) * 1024)
                 : (xsrc + (size_t)(m0 + srow) * xs);
  } else {
    int nrow = ((srow >> 4) << 10) + h0c + (srow & 15);
    grow = sHalf ? (Wh + (size_t)nrow * 1024) : (Wx + (size_t)nrow * wxs);
    KactB = sHalf ? 1024 : Kx;
  }
  const int wbase = ((srow >> 4) << 10) + ((tt & 1) << 9) + ((srow & 15) << 4);
  const int ssec = (isB << 14) + (sHalf << 13);
  const int wHalf = wid >> 2, q = wid & 3;
  const int mb = (q >> 1) << 1, nbb = (q & 1) << 1;
  const int waveNst = wHalf ? 32 : nst0;
  const int secAr = (wHalf << 13);
  const int secBr = 16384 + (wHalf << 13);
  f32x4 accH[4], accL[4];
#pragma unroll
  for (int i = 0; i < 4; ++i) {
    accH[i] = f32x4{0.f, 0.f, 0.f, 0.f};
    accL[i] = f32x4{0.f, 0.f, 0.f, 0.f};
  }
  float4 v[4];
  auto load_regs = [&](int s) {
    const int kl = (s << 5) + kseg;
    const float4* p = (const float4*)(grow + kl);
#pragma unroll
    for (int qq = 0; qq < 4; ++qq) {
      int kk = kl + qq * 4;
      if (kk < KactB) v[qq] = p[qq];
      else v[qq] = float4{0.f, 0.f, 0.f, 0.f};
    }
  };
  auto cvt_write = [&](int buf) {
    char* base = LBUF + buf * 32768 + ssec + wbase;
#pragma unroll
    for (int g = 0; g < 2; ++g) {
      float fs[8] = {v[2*g].x, v[2*g].y, v[2*g].z, v[2*g].w,
                     v[2*g+1].x, v[2*g+1].y, v[2*g+1].z, v[2*g+1].w};
      f16x8 hvv, lvv;
#pragma unroll
      for (int j = 0; j < 8; ++j) {
        _Float16 h16 = (_Float16)fs[j];
        lvv[j] = (_Float16)((fs[j] - (float)h16) * 2048.0f);
        hvv[j] = h16;
      }
      *(f16x8*)(base + g * 256) = hvv;
      *(f16x8*)(base + g * 256 + 4096) = lvv;
    }
  };
  load_regs(0);
  cvt_write(0);
  __syncthreads();
  for (int s = 0; s < nstMax; ++s) {
    const int cur = s & 1, nxt = cur ^ 1;
    const bool doStage = (s + 1 < myNst);
    if (doStage) load_regs(s + 1);
    if (s < waveNst) {
      const char* A0 = LBUF + cur * 32768 + secAr;
      const char* B0 = LBUF + cur * 32768 + secBr;
      f16x8 ah[2], al[2], bh[2], bl[2];
#pragma unroll
      for (int r = 0; r < 2; ++r) {
        ah[r] = *(const f16x8*)(A0 + ((mb + r) << 10) + (lane << 4));
        al[r] = *(const f16x8*)(A0 + 4096 + ((mb + r) << 10) + (lane << 4));
      }
#pragma unroll
      for (int c = 0; c < 2; ++c) {
        bh[c] = *(const f16x8*)(B0 + ((nbb + c) << 10) + (lane << 4));
        bl[c] = *(const f16x8*)(B0 + 4096 + ((nbb + c) << 10) + (lane << 4));
      }
#pragma unroll
      for (int r = 0; r < 2; ++r)
#pragma unroll
        for (int c = 0; c < 2; ++c) {
          int ix = r * 2 + c;
          accH[ix] = __builtin_amdgcn_mfma_f32_16x16x32_f16(ah[r], bh[c], accH[ix], 0, 0, 0);
          accL[ix] = __builtin_amdgcn_mfma_f32_16x16x32_f16(al[r], bh[c], accL[ix], 0, 0, 0);
          accL[ix] = __builtin_amdgcn_mfma_f32_16x16x32_f16(ah[r], bl[c], accL[ix], 0, 0, 0);
        }
    }
    if (doStage) cvt_write(nxt);
    __syncthreads();
  }
  float* GH = (float*)LBUF;
  float* GL = GH + 64 * 68;
  const int mrow0 = ((q >> 1) << 5) + ((lane >> 4) << 2);
  const int ncol0 = ((q & 1) << 5) + (lane & 15);
  if (wHalf == 0) {
#pragma unroll
    for (int r = 0; r < 2; ++r)
#pragma unroll
      for (int c = 0; c < 2; ++c) {
        f32x4 aHh = accH[r * 2 + c], aLl = accL[r * 2 + c];
        int mr = mrow0 + r * 16, nc = ncol0 + c * 16;
#pragma unroll
        for (int i = 0; i < 4; ++i) { GH[(mr + i) * 68 + nc] = aHh[i]; GL[(mr + i) * 68 + nc] = aLl[i]; }
      }
  }
  __syncthreads();
  if (wHalf == 1) {
#pragma unroll
    for (int r = 0; r < 2; ++r)
#pragma unroll
      for (int c = 0; c < 2; ++c) {
        f32x4 aHh = accH[r * 2 + c], aLl = accL[r * 2 + c];
        int mr = mrow0 + r * 16, nc = ncol0 + c * 16;
#pragma unroll
        for (int i = 0; i < 4; ++i) { GH[(mr + i) * 68 + nc] += aHh[i]; GL[(mr + i) * 68 + nc] += aLl[i]; }
      }
  }
  __syncthreads();
  const float LSC = 1.0f / 2048.0f;
#pragma unroll
  for (int e = 0; e < 2; ++e) {
    int ci = tid * 2 + e;
    int bl_ = ci >> 4, hh = ci & 15;
    int b = m0 + bl_, hcol = h0c + hh;
    float xi = GH[bl_ * 68 + hh]      + GL[bl_ * 68 + hh]      * LSC + bcomb[hcol];
    float xf = GH[bl_ * 68 + 16 + hh] + GL[bl_ * 68 + 16 + hh] * LSC + bcomb[1024 + hcol];
    float xg = GH[bl_ * 68 + 32 + hh] + GL[bl_ * 68 + 32 + hh] * LSC + bcomb[2048 + hcol];
    float xo = GH[bl_ * 68 + 48 + hh] + GL[bl_ * 68 + 48 + hh] * LSC + bcomb[3072 + hcol];
    size_t cidx = (size_t)b * 1024 + hcol;
    float cn = fsig(xf) * cbuf[cidx] + fsig(xi) * ftanhf(xg);
    float hn = fsig(xo) * ftanhf(cn);
    cbuf[cidx] = cn;
    hdst[cidx] = hn;
  }
}

__global__ __launch_bounds__(64) void k_decodeO(
    const float* __restrict__ h2, const float* __restrict__ Wdec,
    const float* __restrict__ bdec, const float* __restrict__ emb,
    float* __restrict__ out, float* __restrict__ ebuf, int t) {
  const int b = blockIdx.x, lane = threadIdx.x;
  const float* hrow = h2 + (size_t)b * 1024;
  float logit = 0.f;
  if (lane < OO) {
    const float* wrow = Wdec + (size_t)lane * 1024;
    float p0 = 0.f, p1 = 0.f, p2 = 0.f, p3 = 0.f;
    for (int k = 0; k < 1024; k += 16) {
      float4 w0 = *(const float4*)(wrow + k);      float4 h0v = *(const float4*)(hrow + k);
      float4 w1 = *(const float4*)(wrow + k + 4);  float4 h1v = *(const float4*)(hrow + k + 4);
      float4 w2 = *(const float4*)(wrow + k + 8);  float4 h2v = *(const float4*)(hrow + k + 8);
      float4 w3 = *(const float4*)(wrow + k + 12); float4 h3v = *(const float4*)(hrow + k + 12);
      p0 += w0.x * h0v.x + w0.y * h0v.y + w0.z * h0v.z + w0.w * h0v.w;
      p1 += w1.x * h1v.x + w1.y * h1v.y + w1.z * h1v.z + w1.w * h1v.w;
      p2 += w2.x * h2v.x + w2.y * h2v.y + w2.z * h2v.z + w2.w * h2v.w;
      p3 += w3.x * h3v.x + w3.y * h3v.y + w3.z * h3v.z + w3.w * h3v.w;
    }
    logit = ((p0 + p1) + (p2 + p3)) + bdec[lane];
  }
  float vv = (lane < OO) ? logit : -3.0e38f;
  int idx = (lane < OO) ? lane : 1000;
#pragma unroll
  for (int m = 1; m < 64; m <<= 1) {
    float v2 = __shfl_xor(vv, m, 64);
    int i2 = __shfl_xor(idx, m, 64);
    if (v2 > vv || (v2 == vv && i2 < idx)) { vv = v2; idx = i2; }
  }
  if (lane < OO) out[(size_t)b * (TT * OO) + t * OO + lane] = logit;
  if (t < TT - 1) {
    const float* erow = emb + (size_t)idx * 1024;
#pragma unroll
    for (int i = 0; i < 16; ++i) {
      int h = i * 64 + lane;
      ebuf[(size_t)b * 1056 + h] = erow[h];
    }
  }
}

__global__ void k_finalO(const float* __restrict__ ws, float* __restrict__ out) {
  int i = blockIdx.x * blockDim.x + threadIdx.x;
  int stride = gridDim.x * blockDim.x;
  const int HBASE = BB * TT * OO;
  for (; i < 2 * 786432; i += stride) {
    if (i < 786432) {
      int l = i >> 18, r = i & 262143;
      out[HBASE + i] = ws[O_HP(l, 0) + r];
    } else {
      int j = i - 786432;
      out[HBASE + 786432 + j] = ws[O_CBUF + j];
    }
  }
}

// ---------------------------------------------------------------------------
extern "C" void kernel_launch(void* const* d_in, const int* in_sizes, int n_in,
                              void* d_out, int out_size, void* d_ws, size_t ws_size,
                              hipStream_t stream) {
  const float* props = (const float*)d_in[1];
  const float* emb   = (const float*)d_in[2];
  const float* Wdec  = (const float*)d_in[3];
  const float* bdec  = (const float*)d_in[4];
  const float* Wih0  = (const float*)d_in[5];
  const float* Wihr  = (const float*)d_in[6];
  const float* Whh   = (const float*)d_in[7];
  const float* bih   = (const float*)d_in[8];
  const float* bhh   = (const float*)d_in[9];
  float* out = (float*)d_out;

  if (ws_size >= (size_t)WS_NEEDED) {
    // ---------------- pre-split BK=64 path ----------------
    char* base = (char*)d_ws;
    float* cb = (float*)(base + CBUF_B);
    float* hf = (float*)(base + HF32_B);
    float* bc = (float*)(base + BCOMB_B);
    unsigned short* Ehi = (unsigned short*)(base + EHI_B);
    unsigned short* Elo = (unsigned short*)(base + ELO_B);
    auto HS = [&](int l, int p, int prec) {
      return (unsigned short*)(base + HS_B + (size_t)((l * 2 + p) * 2 + prec) * 524288u);
    };
    unsigned short* Wp[12];
    {
      size_t off = W_B;
      Wp[0] = (unsigned short*)(base + off); off += 8912896u;   // Wx0 hi (34ch)
      Wp[1] = (unsigned short*)(base + off); off += 8912896u;   // Wx0 lo
      for (int i = 2; i < 12; ++i) { Wp[i] = (unsigned short*)(base + off); off += 8388608u; }
      // 2,3=Wh0  4,5=Wx1  6,7=Wh1  8,9=Wx2  10,11=Wh2
    }

    k_zero<<<2048, 256, 0, stream>>>((float*)base, 2359296);          // cbuf+hf32
    k_zero<<<2048, 256, 0, stream>>>((float*)(base + HS_B), 1572864); // h split bufs
    k_binit<<<48, 256, 0, stream>>>(bc, bih, bhh);
    k_einit<<<256, 256, 0, stream>>>(Ehi, Elo, emb, props);
    k_prepw<<<4096, 256, 0, stream>>>(Wih0, Wp[0], Wp[1], 1028, 34);
    k_prepw<<<4096, 256, 0, stream>>>(Whh,                           Wp[2], Wp[3], 1024, 32);
    k_prepw<<<4096, 256, 0, stream>>>(Wihr,                          Wp[4], Wp[5], 1024, 32);
    k_prepw<<<4096, 256, 0, stream>>>(Whh + (size_t)4096 * 1024,     Wp[6], Wp[7], 1024, 32);
    k_prepw<<<4096, 256, 0, stream>>>(Wihr + (size_t)4096 * 1024,    Wp[8], Wp[9], 1024, 32);
    k_prepw<<<4096, 256, 0, stream>>>(Whh + (size_t)2 * 4096 * 1024, Wp[10], Wp[11], 1024, 32);

    for (int t = 0; t < TT; ++t) {
      const int p = t & 1, pn = p ^ 1;
      k_layer<<<256, 512, 0, stream>>>(
          (const char*)Ehi, (const char*)Elo, 34, 17,
          (const char*)HS(0, p, 0), (const char*)HS(0, p, 1),
          (const char*)Wp[0], (const char*)Wp[1],
          (const char*)Wp[2], (const char*)Wp[3],
          bc, cb, hf + (size_t)(0 * 2 + pn) * 262144,
          HS(0, pn, 0), HS(0, pn, 1));
      k_layer<<<256, 512, 0, stream>>>(
          (const char*)HS(0, pn, 0), (const char*)HS(0, pn, 1), 32, 16,
          (const char*)HS(1, p, 0), (const char*)HS(1, p, 1),
          (const char*)Wp[4], (const char*)Wp[5],
          (const char*)Wp[6], (const char*)Wp[7],
          bc + 4096, cb + 262144, hf + (size_t)(1 * 2 + pn) * 262144,
          HS(1, pn, 0), HS(1, pn, 1));
      k_layer<<<256, 512, 0, stream>>>(
          (const char*)HS(1, pn, 0), (const char*)HS(1, pn, 1), 32, 16,
          (const char*)HS(2, p, 0), (const char*)HS(2, p, 1),
          (const char*)Wp[8], (const char*)Wp[9],
          (const char*)Wp[10], (const char*)Wp[11],
          bc + 8192, cb + 524288, hf + (size_t)(2 * 2 + pn) * 262144,
          HS(2, pn, 0), HS(2, pn, 1));
      k_decode<<<256, 256, 0, stream>>>(hf + (size_t)(2 * 2 + pn) * 262144,
                                        Wdec, bdec, emb, out, Ehi, Elo, t);
    }
    k_final<<<2048, 256, 0, stream>>>(hf, cb, out);
  } else {
    // ---------------- legacy R4 path ----------------
    float* ws = (float*)d_ws;
    float* E  = ws + O_EBUF;
    float* cb = ws + O_CBUF;
    float* bc = ws + O_BCOMB;
    k_zero<<<2048, 256, 0, stream>>>(ws, O_WSN);
    k_initO<<<1104, 256, 0, stream>>>(ws, props, emb, bih, bhh);
    for (int t = 0; t < TT; ++t) {
      const int p = t & 1;
      k_layerO<<<256, 512, 0, stream>>>(E, 1056, 1028, 33, ws + O_HP(0, p),
                                        Wih0, 1028, Whh, bc, cb, ws + O_HP(0, p ^ 1));
      k_layerO<<<256, 512, 0, stream>>>(ws + O_HP(0, p ^ 1), 1024, 1024, 32,
                                        ws + O_HP(1, p), Wihr, 1024,
                                        Whh + (size_t)4096 * 1024,
                                        bc + 4096, cb + 262144, ws + O_HP(1, p ^ 1));
      k_layerO<<<256, 512, 0, stream>>>(ws + O_HP(1, p ^ 1), 1024, 1024, 32,
                                        ws + O_HP(2, p),
                                        Wihr + (size_t)4096 * 1024, 1024,
                                        Whh + (size_t)2 * 4096 * 1024,
                                        bc + 8192, cb + 524288, ws + O_HP(2, p ^ 1));
      k_decodeO<<<256, 64, 0, stream>>>(ws + O_HP(2, p ^ 1), Wdec, bdec, emb, out, E, t);
    }
    k_finalO<<<2048, 256, 0, stream>>>(ws, out);
  }
}